// Round 13
// baseline (858.912 us; speedup 1.0000x reference)
//
#include <hip/hip_runtime.h>
#include <math.h>

// B=16, N=8192, L=512, D=384, FF=1536. INPUTS fp32, OUTPUT fp32.
// Round-12 base + FUSED ATTENTION: exp(QK^T) and PV merged into one
// flash-style kernel; P (67MB/group write+read) never materialized. S tile
// lives in XOR-swizzled LDS; parts written unnormalized bf16; reduce divides
// by den. Algebraic folds kept: q2 = scale*qb@wk^T (no K GEMM), wvo = wv@wo
// (no V GEMM; knT from dual-output LayerNorm). Native bf16 pack everywhere.

typedef unsigned short u16;
typedef unsigned int   u32;
typedef __bf16 bf16_t;
typedef bf16_t bf16x8 __attribute__((ext_vector_type(8)));
typedef float  floatx4 __attribute__((ext_vector_type(4)));

__device__ __forceinline__ float b2f(u16 v) {
    return __uint_as_float(((u32)v) << 16);
}
__device__ __forceinline__ u16 f2b(float f) {
    bf16_t h = (bf16_t)f;
    return __builtin_bit_cast(u16, h);
}
__device__ __forceinline__ void stb4(u16* p, float4 f) {
    uint2 v;
    v.x = (u32)f2b(f.x) | ((u32)f2b(f.y) << 16);
    v.y = (u32)f2b(f.z) | ((u32)f2b(f.w) << 16);
    *(uint2*)p = v;
}

// async global->LDS, 16B per lane; LDS dest is wave-uniform base + lane*16.
__device__ __forceinline__ void gl2lds16(u16* lds, const u16* g) {
    __builtin_amdgcn_global_load_lds(
        (const __attribute__((address_space(1))) void*)g,
        (__attribute__((address_space(3))) void*)lds, 16, 0, 0);
}

// Bijective XCD-chunked remap, x-fastest linearization. Identity if nb%8.
__device__ __forceinline__ void xcd_remap(int& bx, int& by, int& bz) {
    int gx = gridDim.x, gy = gridDim.y, gz = gridDim.z;
    int nb = gx * gy * gz;
    int p = bx + gx * (by + gy * bz);
    if ((nb & 7) == 0) {
        int chunk = nb >> 3;
        p = (p & 7) * chunk + (p >> 3);
    }
    bx = p % gx;
    int t = p / gx;
    by = t % gy;
    bz = t / gy;
}

// y-fastest variant: blocks sharing an A-panel are consecutive -> colocated.
__device__ __forceinline__ void xcd_remap_yf(int& bx, int& by, int& bz) {
    int gx = gridDim.x, gy = gridDim.y, gz = gridDim.z;
    int nb = gx * gy * gz;
    int p = by + gy * (bx + gx * bz);
    if ((nb & 7) == 0) {
        int chunk = nb >> 3;
        p = (p & 7) * chunk + (p >> 3);
    }
    by = p % gy;
    int t = p / gy;
    bx = t % gx;
    bz = t / gx;
}

// ---------------------------------------------------------------------------
// All-weights convert in ONE launch. Transposed segments: W [Kd][Nd] ->
// WT bf16 [Nd][Kd]. Natural-layout extracts: wkdir = wkv[:, :384] rows,
// wvdir = wkv[:, 384:768] rows.
__global__ __launch_bounds__(256) void wconv_all(
    const float* __restrict__ w1, const float* __restrict__ w2,
    const float* __restrict__ w3, const float* __restrict__ wq,
    const float* __restrict__ wkv, const float* __restrict__ wo,
    const float* __restrict__ ffw1, const float* __restrict__ ffw2,
    u16* __restrict__ d1, u16* __restrict__ d2, u16* __restrict__ d3,
    u16* __restrict__ dq, u16* __restrict__ dо,
    u16* __restrict__ dffw1, u16* __restrict__ dffw2,
    u16* __restrict__ dwkd, u16* __restrict__ dwvd)
{
    int idx = blockIdx.x * 256 + threadIdx.x;
    if (idx >= 2801664) return;
    if (idx >= 2654208) {                 // wvdir: wkv[d][384+c]
        int local = idx - 2654208;
        int dd = local / 384, c = local - dd * 384;
        dwvd[local] = f2b(wkv[(long long)dd * 768 + 384 + c]);
        return;
    }
    if (idx >= 2506752) {                 // wkdir: wkv[e][d], d<384
        int local = idx - 2506752;
        int e = local / 384, d = local - e * 384;
        dwkd[local] = f2b(wkv[(long long)e * 768 + d]);
        return;
    }
    const float* W; u16* WT; int Kd, Nd, local;
    if      (idx <  147456) { W=w1;   WT=d1;    Kd=384;  Nd=384;  local=idx; }
    else if (idx <  294912) { W=w2;   WT=d2;    Kd=384;  Nd=384;  local=idx-147456; }
    else if (idx <  442368) { W=w3;   WT=d3;    Kd=384;  Nd=384;  local=idx-294912; }
    else if (idx <  589824) { W=wq;   WT=dq;    Kd=384;  Nd=384;  local=idx-442368; }
    else if (idx <  737280) { W=wo;   WT=dо;    Kd=384;  Nd=384;  local=idx-589824; }
    else if (idx < 1916928) { W=ffw1; WT=dffw1; Kd=384;  Nd=3072; local=idx-737280; }
    else                    { W=ffw2; WT=dffw2; Kd=1536; Nd=384;  local=idx-1916928; }
    int n = local / Kd, k = local - n * Kd;
    WT[local] = f2b(W[(long long)k * Nd + n]);
}

// ---------------------------------------------------------------------------
// Layer 0: h = relu(x @ w0 + b0); x fp32 [M][3], out bf16
__global__ __launch_bounds__(256) void layer0_kernel(
    const float* __restrict__ X, const float* __restrict__ W0,
    const float* __restrict__ B0, u16* __restrict__ H, int total4)
{
    int idx = blockIdx.x * 256 + threadIdx.x;
    if (idx >= total4) return;
    int e = idx * 4;
    int m = e / 384;
    int j = e - m * 384;
    float x0 = X[m * 3 + 0], x1 = X[m * 3 + 1], x2 = X[m * 3 + 2];
    float4 w0 = *(const float4*)(W0 + j);
    float4 w1 = *(const float4*)(W0 + 384 + j);
    float4 w2 = *(const float4*)(W0 + 768 + j);
    float4 bb = *(const float4*)(B0 + j);
    float4 v;
    v.x = fmaxf(bb.x + x0 * w0.x + x1 * w1.x + x2 * w2.x, 0.f);
    v.y = fmaxf(bb.y + x0 * w0.y + x1 * w1.y + x2 * w2.y, 0.f);
    v.z = fmaxf(bb.z + x0 * w0.z + x1 * w1.z + x2 * w2.z, 0.f);
    v.w = fmaxf(bb.w + x0 * w0.w + x1 * w1.w + x2 * w2.w, 0.f);
    stb4(H + e, v);
}

// ---------------------------------------------------------------------------
// LayerNorm; input fp32 (IN_F32=1) or bf16; g,b fp32; out bf16. 4 rows/block.
template<int IN_F32>
__global__ __launch_bounds__(256) void ln_kernel(
    const void* __restrict__ Xv, const float* __restrict__ g,
    const float* __restrict__ b, u16* __restrict__ Y, int rows)
{
    int w = threadIdx.x >> 6, lane = threadIdx.x & 63;
    int row = blockIdx.x * 4 + w;
    if (row >= rows) return;
    float v[6];
    float s = 0.f, ss = 0.f;
#pragma unroll
    for (int i = 0; i < 6; ++i) {
        int c = i * 64 + lane;
        v[i] = IN_F32 ? ((const float*)Xv)[(long long)row * 384 + c]
                      : b2f(((const u16*)Xv)[(long long)row * 384 + c]);
        s += v[i]; ss += v[i] * v[i];
    }
#pragma unroll
    for (int m = 32; m; m >>= 1) {
        s  += __shfl_xor(s, m, 64);
        ss += __shfl_xor(ss, m, 64);
    }
    float mean = s * (1.0f / 384.0f);
    float var  = ss * (1.0f / 384.0f) - mean * mean;
    float rs = rsqrtf(fmaxf(var, 0.f) + 1e-5f);
    u16* yr = Y + (long long)row * 384;
#pragma unroll
    for (int i = 0; i < 6; ++i) {
        int c = i * 64 + lane;
        yr[c] = f2b((v[i] - mean) * rs * g[c] + b[c]);
    }
}

// ---------------------------------------------------------------------------
// LayerNorm with dual output: Y [MG][384] natural AND YT [G][384][8192]
// transposed. 64 rows/block; LDS transpose with pad-72.
__global__ __launch_bounds__(256) void ln_tr_kernel(
    const u16* __restrict__ Xv, const float* __restrict__ g,
    const float* __restrict__ b, u16* __restrict__ Y, u16* __restrict__ YT)
{
    __shared__ u16 tr[384 * 72];          // 55296 B
    int w = threadIdx.x >> 6, lane = threadIdx.x & 63;
    int row0 = blockIdx.x * 64;
    for (int rr = 0; rr < 16; ++rr) {
        int jl = w * 16 + rr;
        long long row = row0 + jl;
        float v[6];
        float s = 0.f, ss = 0.f;
#pragma unroll
        for (int i = 0; i < 6; ++i) {
            int c = i * 64 + lane;
            v[i] = b2f(Xv[row * 384 + c]);
            s += v[i]; ss += v[i] * v[i];
        }
#pragma unroll
        for (int m = 32; m; m >>= 1) {
            s  += __shfl_xor(s, m, 64);
            ss += __shfl_xor(ss, m, 64);
        }
        float mean = s * (1.0f / 384.0f);
        float var  = ss * (1.0f / 384.0f) - mean * mean;
        float rs = rsqrtf(fmaxf(var, 0.f) + 1e-5f);
        u16* yr = Y + row * 384;
#pragma unroll
        for (int i = 0; i < 6; ++i) {
            int c = i * 64 + lane;
            u16 val = f2b((v[i] - mean) * rs * g[c] + b[c]);
            yr[c] = val;
            tr[c * 72 + jl] = val;
        }
    }
    __syncthreads();
    int gb = row0 >> 13;
    int jloc = row0 & 8191;
    u16* yt = YT + (long long)gb * 384 * 8192 + jloc;
    for (int e = threadIdx.x; e < 384; e += 256) {
        const u16* src = &tr[e * 72];
        u16* dst = yt + (long long)e * 8192;
#pragma unroll
        for (int q = 0; q < 8; ++q)
            *(uint4*)(dst + q * 8) = *(const uint4*)(src + q * 8);
    }
}

// ---------------------------------------------------------------------------
// 3-buffer pipelined 128x128 K-loop. As_i @ i*4096, Bs_i @ 12288+i*4096 (48KB)
#define STAGE_AB3(bufi, kk)                                                    \
    { u16* asd_ = shmem + (bufi) * 4096;                                       \
      u16* bsd_ = shmem + 12288 + (bufi) * 4096;                               \
      gl2lds16(asd_ + (wv * 32) * 32,                                          \
          aptr_ + (long long)(m0 + wv * 32 + rlo_) * lda_ + (kk) + c8_);       \
      gl2lds16(asd_ + (wv * 32 + 16) * 32,                                     \
          aptr_ + (long long)(m0 + wv * 32 + 16 + rlo_) * lda_ + (kk) + c8_);  \
      gl2lds16(bsd_ + (wv * 32) * 32,                                          \
          bptr_ + (long long)(n0 + wv * 32 + rlo_) * ldb_ + (kk) + c8_);       \
      gl2lds16(bsd_ + (wv * 32 + 16) * 32,                                     \
          bptr_ + (long long)(n0 + wv * 32 + 16 + rlo_) * ldb_ + (kk) + c8_); }

#define MFMA_TILE_PIPE(Aptr, Bptr, LDA, LDB, K0, K1)                           \
    {                                                                          \
        const u16* aptr_ = (Aptr); const u16* bptr_ = (Bptr);                  \
        const long long lda_ = (LDA), ldb_ = (LDB);                            \
        const int rlo_ = lane >> 2, c8_ = (lane & 3) * 8;                      \
        const int T_ = ((K1) - (K0)) >> 5;                                     \
        STAGE_AB3(0, (K0))                                                     \
        STAGE_AB3(1, (K0) + 32)                                                \
        int cur = 0;                                                           \
        for (int t = 0; t < T_; ++t) {                                         \
            if (t + 1 < T_) { asm volatile("s_waitcnt vmcnt(4)" ::: "memory"); } \
            else            { asm volatile("s_waitcnt vmcnt(0)" ::: "memory"); } \
            __builtin_amdgcn_s_barrier();                                      \
            if (t + 2 < T_) {                                                  \
                int stg = (cur == 0) ? 2 : cur - 1;                            \
                STAGE_AB3(stg, (K0) + (t + 2) * 32)                            \
            }                                                                  \
            const u16* As_ = shmem + cur * 4096;                               \
            const u16* Bs_ = shmem + 12288 + cur * 4096;                       \
            bf16x8 a0 = *(const bf16x8*)&As_[(wv * 32 + lr) * 32 + lq * 8];    \
            bf16x8 a1 = *(const bf16x8*)&As_[(wv * 32 + 16 + lr) * 32 + lq * 8]; \
            _Pragma("unroll")                                                  \
            for (int ns = 0; ns < 8; ++ns) {                                   \
                bf16x8 b = *(const bf16x8*)&Bs_[(ns * 16 + lr) * 32 + lq * 8]; \
                acc[0][ns] = __builtin_amdgcn_mfma_f32_16x16x32_bf16(a0, b, acc[0][ns], 0, 0, 0); \
                acc[1][ns] = __builtin_amdgcn_mfma_f32_16x16x32_bf16(a1, b, acc[1][ns], 0, 0, 0); \
            }                                                                  \
            cur = (cur == 2) ? 0 : cur + 1;                                    \
        }                                                                      \
    }

// Generic GEMM with z-strides: C = act(scale*A@WT^T + bias) + res.
template<int RES_F32, int OUT_F32>
__global__ __launch_bounds__(256) void gemm_mfma(
    const u16* __restrict__ A, const u16* __restrict__ WT,
    const float* __restrict__ bias, const void* __restrict__ res,
    void* __restrict__ C,
    int M, int N, int K, int lda, int ldb, int ldc, int ldres,
    float scale, int relu, int resmask,
    long long zsA, long long zsB, long long zsC)
{
    __shared__ u16 shmem[24576];
    const int tid = threadIdx.x;
    const int wv = tid >> 6, lane = tid & 63;
    const int lr = lane & 15, lq = lane >> 4;
    int bx = blockIdx.x, by = blockIdx.y, bz = blockIdx.z;
    xcd_remap_yf(bx, by, bz);
    const int m0 = bx * 128;
    const int n0 = by * 128;
    const u16* Az = A + bz * zsA;
    const u16* Bz = WT + bz * zsB;
    const long long czoff = bz * zsC;

    floatx4 acc[2][8];
#pragma unroll
    for (int i = 0; i < 2; ++i)
#pragma unroll
        for (int j = 0; j < 8; ++j)
            acc[i][j] = (floatx4){0.f, 0.f, 0.f, 0.f};

    MFMA_TILE_PIPE(Az, Bz, lda, ldb, 0, K)

    float bi[8];
#pragma unroll
    for (int ns = 0; ns < 8; ++ns)
        bi[ns] = bias ? bias[n0 + ns * 16 + lr] : 0.f;

#pragma unroll
    for (int ms = 0; ms < 2; ++ms) {
#pragma unroll
        for (int r = 0; r < 4; ++r) {
            int m = m0 + wv * 32 + ms * 16 + lq * 4 + r;
#pragma unroll
            for (int ns = 0; ns < 8; ++ns) {
                int col = n0 + ns * 16 + lr;
                float v = acc[ms][ns][r] * scale + bi[ns];
                if (relu) v = fmaxf(v, 0.f);
                if (res) {
                    long long ro = (long long)(m & resmask) * ldres + col;
                    v += RES_F32 ? ((const float*)res)[ro]
                                 : b2f(((const u16*)res)[ro]);
                }
                long long co = czoff + (long long)m * ldc + col;
                if (OUT_F32) ((float*)C)[co] = v;
                else         ((u16*)C)[co] = f2b(v);
            }
        }
    }
}

// ---------------------------------------------------------------------------
// FUSED ATTENTION: per block, 64 q-rows x full 384-d output over one key
// chunk (8192/SPLIT keys). Per 128-key window: 12-step QK dbuf -> exp into
// XOR-swizzled S (16KB LDS) -> 4-step PV (A=S, B=knT). Parts unnormalized
// bf16; den accumulated via atomics. 512 threads (8 waves: 4 row-groups x
// 2 key/d-halves). LDS 64KB -> 2 blocks/CU.
#define STAGE_QK(bi, kt)                                                       \
    { int rw_ = tid >> 2, qt_ = tid & 3;                                       \
      gl2lds16(QBs[bi] + tid * 8,                                              \
          KN + (knbase + key0 + rw_) * 384 + (kt) * 32 + qt_ * 8);             \
      if (tid < 256)                                                           \
          gl2lds16(QAs[bi] + tid * 8,                                          \
              Q2 + (long long)(q0 + rw_) * 384 + (kt) * 32 + qt_ * 8); }

__global__ __launch_bounds__(512) void attn_fused(
    const u16* __restrict__ Q2, const u16* __restrict__ KN,
    const u16* __restrict__ KT, float* __restrict__ den,
    u16* __restrict__ part, int SPLIT)
{
    __shared__ u16 shmem[32768];   // 64 KB (u16 elems)
    u16* S = shmem;                         // [64][128]  (8192)
    u16* QAs[2] = { shmem + 8192,  shmem + 10240 };   // [64][32] each
    u16* QBs[2] = { shmem + 12288, shmem + 16384 };   // [128][32] each
    u16* PB = shmem + 20480;                // [384][32]  (12288)

    const int tid = threadIdx.x;
    const int lane = tid & 63;
    const int lr = lane & 15, lq = lane >> 4;
    const int w8 = tid >> 6;
    const int rg = w8 >> 1, half = w8 & 1;
    int bx = blockIdx.x, by = blockIdx.y;
    {   // x-fastest chunked remap: same-by (shared kn window) -> same XCD;
        // with SPLIT=8, batch g == XCD index.
        int nb = gridDim.x * gridDim.y;
        int p = bx + gridDim.x * by;
        if ((nb & 7) == 0) { int ch = nb >> 3; p = (p & 7) * ch + (p >> 3); }
        bx = p % gridDim.x; by = p / gridDim.x;
    }
    const int q0 = bx * 64;
    const int z = by;
    const int g = z / SPLIT, sp = z - g * SPLIT;
    const int chunk = 8192 / SPLIT;
    const int windows = chunk >> 7;
    const long long knbase = (long long)g * 8192;
    const u16* KTg = KT + (long long)g * 384 * 8192;

    floatx4 oacc[12];
#pragma unroll
    for (int i = 0; i < 12; ++i) oacc[i] = (floatx4){0.f, 0.f, 0.f, 0.f};
    float denacc[4] = {0.f, 0.f, 0.f, 0.f};

    for (int kw = 0; kw < windows; ++kw) {
        const long long key0 = (long long)sp * chunk + kw * 128;

        // ---- QK: sacc = q2[64 rows] @ kn[128 keys]^T (wave: 16q x 64k) ----
        floatx4 sacc[4];
#pragma unroll
        for (int i = 0; i < 4; ++i) sacc[i] = (floatx4){0.f, 0.f, 0.f, 0.f};
        STAGE_QK(0, 0)
        int cur = 0;
        for (int t = 0; t < 12; ++t) {
            __syncthreads();
            if (t + 1 < 12) STAGE_QK(cur ^ 1, t + 1)
            bf16x8 a = *(const bf16x8*)&QAs[cur][(rg * 16 + lr) * 32 + lq * 8];
#pragma unroll
            for (int nt = 0; nt < 4; ++nt) {
                bf16x8 b = *(const bf16x8*)&QBs[cur][(half * 64 + nt * 16 + lr) * 32 + lq * 8];
                sacc[nt] = __builtin_amdgcn_mfma_f32_16x16x32_bf16(a, b, sacc[nt], 0, 0, 0);
            }
            cur ^= 1;
        }
        __syncthreads();               // prev-window PV reads of S complete
        // ---- exp -> S (swizzled), den partials ----
#pragma unroll
        for (int nt = 0; nt < 4; ++nt)
#pragma unroll
            for (int r = 0; r < 4; ++r) {
                float l = fminf(fmaxf(sacc[nt][r], -60.f), 60.f);
                float p = __expf(l);
                int qrow = rg * 16 + lq * 4 + r;
                int key = half * 64 + nt * 16 + lr;
                int col = key ^ ((qrow & 7) << 3);
                S[qrow * 128 + col] = f2b(p);
                denacc[r] += p;
            }
        __syncthreads();               // S visible to all waves
        // ---- PV: oacc += S @ knT (wave: 16q x 192d) ----
        for (int ks = 0; ks < 4; ++ks) {
#pragma unroll
            for (int i = 0; i < 3; ++i) {
                int slot = i * 512 + tid;
                int rw = slot >> 2, qt = slot & 3;
                gl2lds16(PB + slot * 8,
                    KTg + (long long)rw * 8192 + key0 + ks * 32 + qt * 8);
            }
            __syncthreads();           // PB staged (barrier drains vmcnt)
            int arow = rg * 16 + lr;
            int acol = (ks * 32 + lq * 8) ^ ((arow & 7) << 3);
            bf16x8 a = *(const bf16x8*)&S[arow * 128 + acol];
#pragma unroll
            for (int nt = 0; nt < 12; ++nt) {
                bf16x8 b = *(const bf16x8*)&PB[(half * 192 + nt * 16 + lr) * 32 + lq * 8];
                oacc[nt] = __builtin_amdgcn_mfma_f32_16x16x32_bf16(a, b, oacc[nt], 0, 0, 0);
            }
            __syncthreads();           // PB consumed before next stage
        }
    }

    // ---- den: reduce across lr lanes, one atomic per row-half ----
#pragma unroll
    for (int r = 0; r < 4; ++r) {
        float s = denacc[r];
        s += __shfl_xor(s, 1, 64);
        s += __shfl_xor(s, 2, 64);
        s += __shfl_xor(s, 4, 64);
        s += __shfl_xor(s, 8, 64);
        if (lr == 0)
            atomicAdd(&den[g * 512 + q0 + rg * 16 + lq * 4 + r], s);
    }
    // ---- epilogue: unnormalized bf16 parts ----
    u16* pz = part + (long long)z * 512 * 384;
#pragma unroll
    for (int r = 0; r < 4; ++r) {
        int qrow = rg * 16 + lq * 4 + r;
#pragma unroll
        for (int nt = 0; nt < 12; ++nt) {
            int d = half * 192 + nt * 16 + lr;
            pz[(long long)(q0 + qrow) * 384 + d] = f2b(oacc[nt][r]);
        }
    }
}

// ---------------------------------------------------------------------------
// PV reduce over group: ao[q][d] = (sum_sp part[...]) / den[q]
__global__ __launch_bounds__(256) void pv_reduce_kernel(
    const u16* __restrict__ part, const float* __restrict__ den,
    u16* __restrict__ AO, int SPLIT)
{
    int idx = blockIdx.x * 256 + threadIdx.x;   // G*512*96 threads
    int q = idx / 96, j = (idx - q * 96) * 4;   // q in [0, G*512)
    int g = q >> 9, ql = q & 511;
    const u16* base = part + ((long long)g * SPLIT * 512 + ql) * 384 + j;
    float4 s = make_float4(0.f, 0.f, 0.f, 0.f);
    for (int sp = 0; sp < SPLIT; ++sp) {
        uint2 v = *(const uint2*)(base + (long long)sp * 512 * 384);
        s.x += b2f((u16)(v.x & 0xffff));
        s.y += b2f((u16)(v.x >> 16));
        s.z += b2f((u16)(v.y & 0xffff));
        s.w += b2f((u16)(v.y >> 16));
    }
    float inv = 1.0f / den[q];
    s.x *= inv; s.y *= inv; s.z *= inv; s.w *= inv;
    stb4(AO + (long long)q * 384 + j, s);
}

// ---------------------------------------------------------------------------
// FF1 + GEGLU fused: gl = a * gelu(g). 128x(64+64) tile, 3-buffer pipeline.
__global__ __launch_bounds__(256) void gemm_ff1_geglu(
    const u16* __restrict__ A, const u16* __restrict__ WT,
    const float* __restrict__ bias, u16* __restrict__ C,
    int K, int lda, int ldb, int ldc)
{
    __shared__ u16 shmem[24576];
    const int tid = threadIdx.x;
    const int wv = tid >> 6, lane = tid & 63;
    const int lr = lane & 15, lq = lane >> 4;
    int bx = blockIdx.x, by = blockIdx.y, bz = blockIdx.z;
    xcd_remap_yf(bx, by, bz);
    const int m0 = bx * 128;
    const int n0 = by * 64;
    const int rlo = lane >> 2, c8 = (lane & 3) * 8;

    floatx4 accA[2][4], accG[2][4];
#pragma unroll
    for (int i = 0; i < 2; ++i)
#pragma unroll
        for (int j = 0; j < 4; ++j) {
            accA[i][j] = (floatx4){0.f, 0.f, 0.f, 0.f};
            accG[i][j] = (floatx4){0.f, 0.f, 0.f, 0.f};
        }

#define STAGE_FF(bufi, kk)                                                     \
    { u16* asd = shmem + (bufi) * 4096;                                        \
      u16* bsd = shmem + 12288 + (bufi) * 4096;                                \
      gl2lds16(asd + (wv * 32) * 32,                                           \
          A + (long long)(m0 + wv * 32 + rlo) * lda + (kk) + c8);              \
      gl2lds16(asd + (wv * 32 + 16) * 32,                                      \
          A + (long long)(m0 + wv * 32 + 16 + rlo) * lda + (kk) + c8);         \
      int r0 = wv * 32 + rlo, r1 = r0 + 16;                                    \
      int wrow0 = (r0 < 64) ? (n0 + r0) : (1536 + n0 + r0 - 64);               \
      int wrow1 = (r1 < 64) ? (n0 + r1) : (1536 + n0 + r1 - 64);               \
      gl2lds16(bsd + (wv * 32) * 32, WT + (long long)wrow0 * ldb + (kk) + c8); \
      gl2lds16(bsd + (wv * 32 + 16) * 32, WT + (long long)wrow1 * ldb + (kk) + c8); }

    const int T = K >> 5;
    STAGE_FF(0, 0)
    STAGE_FF(1, 32)
    int cur = 0;
    for (int t = 0; t < T; ++t) {
        if (t + 1 < T) { asm volatile("s_waitcnt vmcnt(4)" ::: "memory"); }
        else           { asm volatile("s_waitcnt vmcnt(0)" ::: "memory"); }
        __builtin_amdgcn_s_barrier();
        if (t + 2 < T) {
            int stg = (cur == 0) ? 2 : cur - 1;
            STAGE_FF(stg, (t + 2) * 32)
        }
        const u16* As_ = shmem + cur * 4096;
        const u16* Bs_ = shmem + 12288 + cur * 4096;
        bf16x8 a0 = *(const bf16x8*)&As_[(wv * 32 + lr) * 32 + lq * 8];
        bf16x8 a1 = *(const bf16x8*)&As_[(wv * 32 + 16 + lr) * 32 + lq * 8];
#pragma unroll
        for (int ns = 0; ns < 4; ++ns) {
            bf16x8 bA = *(const bf16x8*)&Bs_[(ns * 16 + lr) * 32 + lq * 8];
            bf16x8 bG = *(const bf16x8*)&Bs_[((64 + ns * 16) + lr) * 32 + lq * 8];
            accA[0][ns] = __builtin_amdgcn_mfma_f32_16x16x32_bf16(a0, bA, accA[0][ns], 0, 0, 0);
            accA[1][ns] = __builtin_amdgcn_mfma_f32_16x16x32_bf16(a1, bA, accA[1][ns], 0, 0, 0);
            accG[0][ns] = __builtin_amdgcn_mfma_f32_16x16x32_bf16(a0, bG, accG[0][ns], 0, 0, 0);
            accG[1][ns] = __builtin_amdgcn_mfma_f32_16x16x32_bf16(a1, bG, accG[1][ns], 0, 0, 0);
        }
        cur = (cur == 2) ? 0 : cur + 1;
    }
#undef STAGE_FF

    float ba[4], bg[4];
#pragma unroll
    for (int ns = 0; ns < 4; ++ns) {
        ba[ns] = bias[n0 + ns * 16 + lr];
        bg[ns] = bias[1536 + n0 + ns * 16 + lr];
    }
#pragma unroll
    for (int ms = 0; ms < 2; ++ms)
#pragma unroll
        for (int r = 0; r < 4; ++r) {
            int m = m0 + wv * 32 + ms * 16 + lq * 4 + r;
#pragma unroll
            for (int ns = 0; ns < 4; ++ns) {
                int col = n0 + ns * 16 + lr;
                float a = accA[ms][ns][r] + ba[ns];
                float g = accG[ms][ns][r] + bg[ns];
                float v = a * 0.5f * g * (1.0f + erff(g * 0.70710678118654752f));
                C[(long long)m * ldc + col] = f2b(v);
            }
        }
}

// ---------------------------------------------------------------------------
extern "C" void kernel_launch(void* const* d_in, const int* in_sizes, int n_in,
                              void* d_out, int out_size, void* d_ws, size_t ws_size,
                              hipStream_t stream) {
    const float* x     = (const float*)d_in[0];
    const float* w0    = (const float*)d_in[1];
    const float* b0    = (const float*)d_in[2];
    const float* w1    = (const float*)d_in[3];
    const float* b1    = (const float*)d_in[4];
    const float* w2    = (const float*)d_in[5];
    const float* b2    = (const float*)d_in[6];
    const float* w3    = (const float*)d_in[7];
    const float* b3    = (const float*)d_in[8];
    const float* query = (const float*)d_in[9];
    const float* lnqg  = (const float*)d_in[10];
    const float* lnqb  = (const float*)d_in[11];
    const float* lncg  = (const float*)d_in[12];
    const float* lncb  = (const float*)d_in[13];
    const float* wq    = (const float*)d_in[14];
    const float* wkv   = (const float*)d_in[15];
    const float* wo    = (const float*)d_in[16];
    const float* bo    = (const float*)d_in[17];
    const float* lnfg  = (const float*)d_in[18];
    const float* lnfb  = (const float*)d_in[19];
    const float* ffw1  = (const float*)d_in[20];
    const float* ffb1  = (const float*)d_in[21];
    const float* ffw2  = (const float*)d_in[22];
    const float* ffb2  = (const float*)d_in[23];
    float* out = (float*)d_out;
    char* wsb = (char*)d_ws;

    // ---- group size selection (P buffer eliminated; part fixed 64 slots) --
    auto need = [](int G) -> size_t {
        return (size_t)G * (3LL * 6291456)             // bufA,bufB,knT
             + 25165824                                // part (64 bf16 slots)
             + 6291456                                 // ao_all
             + 3 * 393216 + 32768                      // qn, qb, q2, den
             + 6193152;                                // weight pool
    };
    int G = 2;
    if      (ws_size >= need(16)) G = 16;
    else if (ws_size >= need(8))  G = 8;
    else if (ws_size >= need(4))  G = 4;
    if (G > 8) G = 8;                     // attn grid fixed at 64 z-slots
    const int SPLIT = 64 / G;

    long long off = 0;
    u16*   bufA   = (u16*)(wsb + off); off += (long long)G * 6291456;
    u16*   bufB   = (u16*)(wsb + off); off += (long long)G * 6291456;
    u16*   knT    = (u16*)(wsb + off); off += (long long)G * 6291456;
    u16*   part   = (u16*)(wsb + off); off += 25165824;
    u16*   ao_all = (u16*)(wsb + off); off += 6291456;
    u16*   qn     = (u16*)(wsb + off); off += 393216;
    u16*   qb     = (u16*)(wsb + off); off += 393216;
    u16*   q2     = (u16*)(wsb + off); off += 393216;
    float* den    = (float*)(wsb + off); off += 32768;
    u16*   w1T    = (u16*)(wsb + off); off += 294912;
    u16*   w2T    = (u16*)(wsb + off); off += 294912;
    u16*   w3T    = (u16*)(wsb + off); off += 294912;
    u16*   wqT    = (u16*)(wsb + off); off += 294912;
    u16*   woT    = (u16*)(wsb + off); off += 294912;
    u16*   ffw1T  = (u16*)(wsb + off); off += 2359296;
    u16*   ffw2T  = (u16*)(wsb + off); off += 1179648;
    u16*   wkdir  = (u16*)(wsb + off); off += 294912;   // wk natural layout
    u16*   wvdir  = (u16*)(wsb + off); off += 294912;   // wv natural layout
    u16*   wvoT   = (u16*)(wsb + off); off += 294912;   // (wv wo)^T
    // phase-2 overlays (bufA/bufB/knT region is dead by then)
    u16*   x1_all = (u16*)(wsb + 0);
    u16*   f0_all = (u16*)(wsb + 6291456);
    u16*   gl_all = (u16*)(wsb + 12582912);

    const int FULLMASK = 0x3FFFFFFF;

    // ---- setup ----
    wconv_all<<<10944, 256, 0, stream>>>(w1, w2, w3, wq, wkv, wo, ffw1, ffw2,
        w1T, w2T, w3T, wqT, woT, ffw1T, ffw2T, wkdir, wvdir);
    hipMemsetAsync(den, 0, 16 * 512 * sizeof(float), stream);
    ln_kernel<1><<<128, 256, 0, stream>>>(query, lnqg, lnqb, qn, 512);
    gemm_mfma<0, 0><<<dim3(4, 3), 256, 0, stream>>>(qn, wqT, nullptr, nullptr, qb,
        512, 384, 384, 384, 384, 384, 0, 1.f, 0, FULLMASK, 0, 0, 0);
    // q2 = scale * (qb @ wk^T)
    gemm_mfma<0, 0><<<dim3(4, 3), 256, 0, stream>>>(qb, wkdir, nullptr, nullptr, q2,
        512, 384, 384, 384, 384, 384, 0, 0.05103103630798288f, 0, FULLMASK, 0, 0, 0);
    // wvoT[o][d] = sum_c woT[o][c] * wv[d][c] = ((wv)(wo))^T
    gemm_mfma<0, 0><<<dim3(3, 3), 256, 0, stream>>>(woT, wvdir, nullptr, nullptr, wvoT,
        384, 384, 384, 384, 384, 384, 0, 1.f, 0, FULLMASK, 0, 0, 0);

    // ---- phase 1: groups of G batches ----
    const int MG = G * 8192;
    for (int base = 0; base < 16; base += G) {
        const float* xg = x + (long long)base * 24576;

        layer0_kernel<<<G * 3072, 256, 0, stream>>>(xg, w0, b0, bufA, G * 786432);
        gemm_mfma<0, 0><<<dim3(MG / 128, 3), 256, 0, stream>>>(bufA, w1T, b1, nullptr, bufB,
            MG, 384, 384, 384, 384, 384, 0, 1.f, 1, FULLMASK, 0, 0, 0);
        gemm_mfma<0, 0><<<dim3(MG / 128, 3), 256, 0, stream>>>(bufB, w2T, b2, nullptr, bufA,
            MG, 384, 384, 384, 384, 384, 0, 1.f, 1, FULLMASK, 0, 0, 0);
        gemm_mfma<0, 0><<<dim3(MG / 128, 3), 256, 0, stream>>>(bufA, w3T, b3, nullptr, bufB,
            MG, 384, 384, 384, 384, 384, 0, 1.f, 0, FULLMASK, 0, 0, 0);   // ctx -> bufB
        // kn (natural -> bufA) AND kn^T (-> knT) in one LayerNorm pass
        ln_tr_kernel<<<MG / 64, 256, 0, stream>>>(bufB, lncg, lncb, bufA, knT);
        // FUSED attention: exp(q2@kn^T) -> S(LDS) -> S@knT; parts + den
        attn_fused<<<dim3(8, 64), 512, 0, stream>>>(q2, bufA, knT,
            den + base * 512, part, SPLIT);
        // reduce (divide by den) -> ao_all[base..base+G)
        pv_reduce_kernel<<<G * 192, 256, 0, stream>>>(part, den + base * 512,
            ao_all + (long long)base * 196608, SPLIT);
    }

    // ---- phase 2: batched across all 16 ----
    // x1 = ao2 @ (wv wo) + bo + lq   (V-projection folded into wvo)
    gemm_mfma<1, 0><<<dim3(64, 3), 256, 0, stream>>>(ao_all, wvoT, bo, query, x1_all,
        8192, 384, 384, 384, 384, 384, 384, 1.f, 0, 511, 0, 0, 0);
    ln_kernel<0><<<2048, 256, 0, stream>>>(x1_all, lnfg, lnfb, f0_all, 8192);
    gemm_ff1_geglu<<<dim3(64, 24), 256, 0, stream>>>(f0_all, ffw1T, ffb1, gl_all,
        384, 384, 384, 1536);
    gemm_mfma<0, 1><<<dim3(64, 3), 256, 0, stream>>>(gl_all, ffw2T, ffb2, x1_all, out,
        8192, 384, 1536, 1536, 1536, 384, 384, 1.f, 0, FULLMASK, 0, 0, 0);
}

// Round 14
// 765.436 us; speedup vs baseline: 1.1221x; 1.1221x over previous
//
#include <hip/hip_runtime.h>
#include <math.h>

// B=16, N=8192, L=512, D=384, FF=1536. INPUTS fp32, OUTPUT fp32.
// Round-12 configuration (best verified: 768us). Algebraic eliminations:
// (1) K-projection folded into q2 = qb@wk^T (no K_all GEMM); (2) V-projection
// folded: out@wo = (attn@kn)@(wv wo), PV consumes kn^T directly, phase-2 uses
// wvo = wv@wo; kn^T comes from the dual-output ctx LayerNorm (ln_tr).
// Round-13's fused attention REVERTED (149us vs 95us pair: 22 barriers/window
// + LDS bank conflicts beat the P-traffic saving). 128x128 3-buffer pipelined
// K-loop for long-K gemms; exp: 2-phase 32KB dbuf + swizzled LDS-transpose
// epilogue. Native bf16 pack everywhere.

typedef unsigned short u16;
typedef unsigned int   u32;
typedef __bf16 bf16_t;
typedef bf16_t bf16x8 __attribute__((ext_vector_type(8)));
typedef float  floatx4 __attribute__((ext_vector_type(4)));

__device__ __forceinline__ float b2f(u16 v) {
    return __uint_as_float(((u32)v) << 16);
}
__device__ __forceinline__ u16 f2b(float f) {
    bf16_t h = (bf16_t)f;
    return __builtin_bit_cast(u16, h);
}
__device__ __forceinline__ void stb4(u16* p, float4 f) {
    uint2 v;
    v.x = (u32)f2b(f.x) | ((u32)f2b(f.y) << 16);
    v.y = (u32)f2b(f.z) | ((u32)f2b(f.w) << 16);
    *(uint2*)p = v;
}

// async global->LDS, 16B per lane; LDS dest is wave-uniform base + lane*16.
__device__ __forceinline__ void gl2lds16(u16* lds, const u16* g) {
    __builtin_amdgcn_global_load_lds(
        (const __attribute__((address_space(1))) void*)g,
        (__attribute__((address_space(3))) void*)lds, 16, 0, 0);
}

// Bijective XCD-chunked remap, x-fastest linearization. Identity if nb%8.
__device__ __forceinline__ void xcd_remap(int& bx, int& by, int& bz) {
    int gx = gridDim.x, gy = gridDim.y, gz = gridDim.z;
    int nb = gx * gy * gz;
    int p = bx + gx * (by + gy * bz);
    if ((nb & 7) == 0) {
        int chunk = nb >> 3;
        p = (p & 7) * chunk + (p >> 3);
    }
    bx = p % gx;
    int t = p / gx;
    by = t % gy;
    bz = t / gy;
}

// y-fastest variant: blocks sharing an A-panel are consecutive -> colocated.
__device__ __forceinline__ void xcd_remap_yf(int& bx, int& by, int& bz) {
    int gx = gridDim.x, gy = gridDim.y, gz = gridDim.z;
    int nb = gx * gy * gz;
    int p = by + gy * (bx + gx * bz);
    if ((nb & 7) == 0) {
        int chunk = nb >> 3;
        p = (p & 7) * chunk + (p >> 3);
    }
    by = p % gy;
    int t = p / gy;
    bx = t % gx;
    bz = t / gx;
}

// ---------------------------------------------------------------------------
// All-weights convert in ONE launch. Transposed segments: W [Kd][Nd] ->
// WT bf16 [Nd][Kd]. Natural-layout extracts: wkdir = wkv[:, :384] rows,
// wvdir = wkv[:, 384:768] rows.
__global__ __launch_bounds__(256) void wconv_all(
    const float* __restrict__ w1, const float* __restrict__ w2,
    const float* __restrict__ w3, const float* __restrict__ wq,
    const float* __restrict__ wkv, const float* __restrict__ wo,
    const float* __restrict__ ffw1, const float* __restrict__ ffw2,
    u16* __restrict__ d1, u16* __restrict__ d2, u16* __restrict__ d3,
    u16* __restrict__ dq, u16* __restrict__ dо,
    u16* __restrict__ dffw1, u16* __restrict__ dffw2,
    u16* __restrict__ dwkd, u16* __restrict__ dwvd)
{
    int idx = blockIdx.x * 256 + threadIdx.x;
    if (idx >= 2801664) return;
    if (idx >= 2654208) {                 // wvdir: wkv[d][384+c]
        int local = idx - 2654208;
        int dd = local / 384, c = local - dd * 384;
        dwvd[local] = f2b(wkv[(long long)dd * 768 + 384 + c]);
        return;
    }
    if (idx >= 2506752) {                 // wkdir: wkv[e][d], d<384
        int local = idx - 2506752;
        int e = local / 384, d = local - e * 384;
        dwkd[local] = f2b(wkv[(long long)e * 768 + d]);
        return;
    }
    const float* W; u16* WT; int Kd, Nd, local;
    if      (idx <  147456) { W=w1;   WT=d1;    Kd=384;  Nd=384;  local=idx; }
    else if (idx <  294912) { W=w2;   WT=d2;    Kd=384;  Nd=384;  local=idx-147456; }
    else if (idx <  442368) { W=w3;   WT=d3;    Kd=384;  Nd=384;  local=idx-294912; }
    else if (idx <  589824) { W=wq;   WT=dq;    Kd=384;  Nd=384;  local=idx-442368; }
    else if (idx <  737280) { W=wo;   WT=dо;    Kd=384;  Nd=384;  local=idx-589824; }
    else if (idx < 1916928) { W=ffw1; WT=dffw1; Kd=384;  Nd=3072; local=idx-737280; }
    else                    { W=ffw2; WT=dffw2; Kd=1536; Nd=384;  local=idx-1916928; }
    int n = local / Kd, k = local - n * Kd;
    WT[local] = f2b(W[(long long)k * Nd + n]);
}

// ---------------------------------------------------------------------------
// Layer 0: h = relu(x @ w0 + b0); x fp32 [M][3], out bf16
__global__ __launch_bounds__(256) void layer0_kernel(
    const float* __restrict__ X, const float* __restrict__ W0,
    const float* __restrict__ B0, u16* __restrict__ H, int total4)
{
    int idx = blockIdx.x * 256 + threadIdx.x;
    if (idx >= total4) return;
    int e = idx * 4;
    int m = e / 384;
    int j = e - m * 384;
    float x0 = X[m * 3 + 0], x1 = X[m * 3 + 1], x2 = X[m * 3 + 2];
    float4 w0 = *(const float4*)(W0 + j);
    float4 w1 = *(const float4*)(W0 + 384 + j);
    float4 w2 = *(const float4*)(W0 + 768 + j);
    float4 bb = *(const float4*)(B0 + j);
    float4 v;
    v.x = fmaxf(bb.x + x0 * w0.x + x1 * w1.x + x2 * w2.x, 0.f);
    v.y = fmaxf(bb.y + x0 * w0.y + x1 * w1.y + x2 * w2.y, 0.f);
    v.z = fmaxf(bb.z + x0 * w0.z + x1 * w1.z + x2 * w2.z, 0.f);
    v.w = fmaxf(bb.w + x0 * w0.w + x1 * w1.w + x2 * w2.w, 0.f);
    stb4(H + e, v);
}

// ---------------------------------------------------------------------------
// LayerNorm; input fp32 (IN_F32=1) or bf16; g,b fp32; out bf16. 4 rows/block.
template<int IN_F32>
__global__ __launch_bounds__(256) void ln_kernel(
    const void* __restrict__ Xv, const float* __restrict__ g,
    const float* __restrict__ b, u16* __restrict__ Y, int rows)
{
    int w = threadIdx.x >> 6, lane = threadIdx.x & 63;
    int row = blockIdx.x * 4 + w;
    if (row >= rows) return;
    float v[6];
    float s = 0.f, ss = 0.f;
#pragma unroll
    for (int i = 0; i < 6; ++i) {
        int c = i * 64 + lane;
        v[i] = IN_F32 ? ((const float*)Xv)[(long long)row * 384 + c]
                      : b2f(((const u16*)Xv)[(long long)row * 384 + c]);
        s += v[i]; ss += v[i] * v[i];
    }
#pragma unroll
    for (int m = 32; m; m >>= 1) {
        s  += __shfl_xor(s, m, 64);
        ss += __shfl_xor(ss, m, 64);
    }
    float mean = s * (1.0f / 384.0f);
    float var  = ss * (1.0f / 384.0f) - mean * mean;
    float rs = rsqrtf(fmaxf(var, 0.f) + 1e-5f);
    u16* yr = Y + (long long)row * 384;
#pragma unroll
    for (int i = 0; i < 6; ++i) {
        int c = i * 64 + lane;
        yr[c] = f2b((v[i] - mean) * rs * g[c] + b[c]);
    }
}

// ---------------------------------------------------------------------------
// LayerNorm with dual output: Y [MG][384] natural AND YT [G][384][8192]
// transposed (for the PV GEMM's B operand). 64 rows/block, 4 waves x 16 rows;
// LDS transpose with pad-72 (16B-aligned stripes). bf16 in/out.
__global__ __launch_bounds__(256) void ln_tr_kernel(
    const u16* __restrict__ Xv, const float* __restrict__ g,
    const float* __restrict__ b, u16* __restrict__ Y, u16* __restrict__ YT)
{
    __shared__ u16 tr[384 * 72];          // 55296 B
    int w = threadIdx.x >> 6, lane = threadIdx.x & 63;
    int row0 = blockIdx.x * 64;
    for (int rr = 0; rr < 16; ++rr) {
        int jl = w * 16 + rr;
        long long row = row0 + jl;
        float v[6];
        float s = 0.f, ss = 0.f;
#pragma unroll
        for (int i = 0; i < 6; ++i) {
            int c = i * 64 + lane;
            v[i] = b2f(Xv[row * 384 + c]);
            s += v[i]; ss += v[i] * v[i];
        }
#pragma unroll
        for (int m = 32; m; m >>= 1) {
            s  += __shfl_xor(s, m, 64);
            ss += __shfl_xor(ss, m, 64);
        }
        float mean = s * (1.0f / 384.0f);
        float var  = ss * (1.0f / 384.0f) - mean * mean;
        float rs = rsqrtf(fmaxf(var, 0.f) + 1e-5f);
        u16* yr = Y + row * 384;
#pragma unroll
        for (int i = 0; i < 6; ++i) {
            int c = i * 64 + lane;
            u16 val = f2b((v[i] - mean) * rs * g[c] + b[c]);
            yr[c] = val;
            tr[c * 72 + jl] = val;
        }
    }
    __syncthreads();
    // transposed write-out: row0 is 64-aligned within a batch (8192 rows).
    int gb = row0 >> 13;
    int jloc = row0 & 8191;
    u16* yt = YT + (long long)gb * 384 * 8192 + jloc;
    for (int e = threadIdx.x; e < 384; e += 256) {
        const u16* src = &tr[e * 72];
        u16* dst = yt + (long long)e * 8192;
#pragma unroll
        for (int q = 0; q < 8; ++q)
            *(uint4*)(dst + q * 8) = *(const uint4*)(src + q * 8);
    }
}

// ---------------------------------------------------------------------------
// 3-buffer pipelined 128x128 K-loop. As_i @ i*4096, Bs_i @ 12288+i*4096 (48KB)
#define STAGE_AB3(bufi, kk)                                                    \
    { u16* asd_ = shmem + (bufi) * 4096;                                       \
      u16* bsd_ = shmem + 12288 + (bufi) * 4096;                               \
      gl2lds16(asd_ + (wv * 32) * 32,                                          \
          aptr_ + (long long)(m0 + wv * 32 + rlo_) * lda_ + (kk) + c8_);       \
      gl2lds16(asd_ + (wv * 32 + 16) * 32,                                     \
          aptr_ + (long long)(m0 + wv * 32 + 16 + rlo_) * lda_ + (kk) + c8_);  \
      gl2lds16(bsd_ + (wv * 32) * 32,                                          \
          bptr_ + (long long)(n0 + wv * 32 + rlo_) * ldb_ + (kk) + c8_);       \
      gl2lds16(bsd_ + (wv * 32 + 16) * 32,                                     \
          bptr_ + (long long)(n0 + wv * 32 + 16 + rlo_) * ldb_ + (kk) + c8_); }

#define MFMA_TILE_PIPE(Aptr, Bptr, LDA, LDB, K0, K1)                           \
    {                                                                          \
        const u16* aptr_ = (Aptr); const u16* bptr_ = (Bptr);                  \
        const long long lda_ = (LDA), ldb_ = (LDB);                            \
        const int rlo_ = lane >> 2, c8_ = (lane & 3) * 8;                      \
        const int T_ = ((K1) - (K0)) >> 5;                                     \
        STAGE_AB3(0, (K0))                                                     \
        STAGE_AB3(1, (K0) + 32)                                                \
        int cur = 0;                                                           \
        for (int t = 0; t < T_; ++t) {                                         \
            if (t + 1 < T_) { asm volatile("s_waitcnt vmcnt(4)" ::: "memory"); } \
            else            { asm volatile("s_waitcnt vmcnt(0)" ::: "memory"); } \
            __builtin_amdgcn_s_barrier();                                      \
            if (t + 2 < T_) {                                                  \
                int stg = (cur == 0) ? 2 : cur - 1;                            \
                STAGE_AB3(stg, (K0) + (t + 2) * 32)                            \
            }                                                                  \
            const u16* As_ = shmem + cur * 4096;                               \
            const u16* Bs_ = shmem + 12288 + cur * 4096;                       \
            bf16x8 a0 = *(const bf16x8*)&As_[(wv * 32 + lr) * 32 + lq * 8];    \
            bf16x8 a1 = *(const bf16x8*)&As_[(wv * 32 + 16 + lr) * 32 + lq * 8]; \
            _Pragma("unroll")                                                  \
            for (int ns = 0; ns < 8; ++ns) {                                   \
                bf16x8 b = *(const bf16x8*)&Bs_[(ns * 16 + lr) * 32 + lq * 8]; \
                acc[0][ns] = __builtin_amdgcn_mfma_f32_16x16x32_bf16(a0, b, acc[0][ns], 0, 0, 0); \
                acc[1][ns] = __builtin_amdgcn_mfma_f32_16x16x32_bf16(a1, b, acc[1][ns], 0, 0, 0); \
            }                                                                  \
            cur = (cur == 2) ? 0 : cur + 1;                                    \
        }                                                                      \
    }

// 2-phase double-buffered loop (short-K, epilogue-heavy kernels; 32 KB LDS
// -> 5 blocks/CU). As0 @0, As1 @4096, Bs0 @8192, Bs1 @12288.
#define STAGE_AB2(bufi, kk)                                                    \
    { u16* asd_ = shmem + (bufi) * 4096;                                       \
      u16* bsd_ = shmem + 8192 + (bufi) * 4096;                                \
      gl2lds16(asd_ + (wv * 32) * 32,                                          \
          aptr_ + (long long)(m0 + wv * 32 + rlo_) * lda_ + (kk) + c8_);       \
      gl2lds16(asd_ + (wv * 32 + 16) * 32,                                     \
          aptr_ + (long long)(m0 + wv * 32 + 16 + rlo_) * lda_ + (kk) + c8_);  \
      gl2lds16(bsd_ + (wv * 32) * 32,                                          \
          bptr_ + (long long)(n0 + wv * 32 + rlo_) * ldb_ + (kk) + c8_);       \
      gl2lds16(bsd_ + (wv * 32 + 16) * 32,                                     \
          bptr_ + (long long)(n0 + wv * 32 + 16 + rlo_) * ldb_ + (kk) + c8_); }

#define MFMA_TILE_DBUF(Aptr, Bptr, LDA, LDB, K0, K1)                           \
    {                                                                          \
        const u16* aptr_ = (Aptr); const u16* bptr_ = (Bptr);                  \
        const long long lda_ = (LDA), ldb_ = (LDB);                            \
        const int rlo_ = lane >> 2, c8_ = (lane & 3) * 8;                      \
        int cur = 0;                                                           \
        STAGE_AB2(0, (K0))                                                     \
        for (int k0 = (K0); k0 < (K1); k0 += 32) {                             \
            __syncthreads();                                                   \
            if (k0 + 32 < (K1)) STAGE_AB2(cur ^ 1, k0 + 32)                    \
            const u16* As_ = shmem + cur * 4096;                               \
            const u16* Bs_ = shmem + 8192 + cur * 4096;                        \
            bf16x8 a0 = *(const bf16x8*)&As_[(wv * 32 + lr) * 32 + lq * 8];    \
            bf16x8 a1 = *(const bf16x8*)&As_[(wv * 32 + 16 + lr) * 32 + lq * 8]; \
            _Pragma("unroll")                                                  \
            for (int ns = 0; ns < 8; ++ns) {                                   \
                bf16x8 b = *(const bf16x8*)&Bs_[(ns * 16 + lr) * 32 + lq * 8]; \
                acc[0][ns] = __builtin_amdgcn_mfma_f32_16x16x32_bf16(a0, b, acc[0][ns], 0, 0, 0); \
                acc[1][ns] = __builtin_amdgcn_mfma_f32_16x16x32_bf16(a1, b, acc[1][ns], 0, 0, 0); \
            }                                                                  \
            cur ^= 1;                                                          \
        }                                                                      \
    }

// Generic GEMM with z-strides: C = act(scale*A@WT^T + bias) + res.
template<int RES_F32, int OUT_F32>
__global__ __launch_bounds__(256) void gemm_mfma(
    const u16* __restrict__ A, const u16* __restrict__ WT,
    const float* __restrict__ bias, const void* __restrict__ res,
    void* __restrict__ C,
    int M, int N, int K, int lda, int ldb, int ldc, int ldres,
    float scale, int relu, int resmask,
    long long zsA, long long zsB, long long zsC)
{
    __shared__ u16 shmem[24576];
    const int tid = threadIdx.x;
    const int wv = tid >> 6, lane = tid & 63;
    const int lr = lane & 15, lq = lane >> 4;
    int bx = blockIdx.x, by = blockIdx.y, bz = blockIdx.z;
    xcd_remap_yf(bx, by, bz);
    const int m0 = bx * 128;
    const int n0 = by * 128;
    const u16* Az = A + bz * zsA;
    const u16* Bz = WT + bz * zsB;
    const long long czoff = bz * zsC;

    floatx4 acc[2][8];
#pragma unroll
    for (int i = 0; i < 2; ++i)
#pragma unroll
        for (int j = 0; j < 8; ++j)
            acc[i][j] = (floatx4){0.f, 0.f, 0.f, 0.f};

    MFMA_TILE_PIPE(Az, Bz, lda, ldb, 0, K)

    float bi[8];
#pragma unroll
    for (int ns = 0; ns < 8; ++ns)
        bi[ns] = bias ? bias[n0 + ns * 16 + lr] : 0.f;

#pragma unroll
    for (int ms = 0; ms < 2; ++ms) {
#pragma unroll
        for (int r = 0; r < 4; ++r) {
            int m = m0 + wv * 32 + ms * 16 + lq * 4 + r;
#pragma unroll
            for (int ns = 0; ns < 8; ++ns) {
                int col = n0 + ns * 16 + lr;
                float v = acc[ms][ns][r] * scale + bi[ns];
                if (relu) v = fmaxf(v, 0.f);
                if (res) {
                    long long ro = (long long)(m & resmask) * ldres + col;
                    v += RES_F32 ? ((const float*)res)[ro]
                                 : b2f(((const u16*)res)[ro]);
                }
                long long co = czoff + (long long)m * ldc + col;
                if (OUT_F32) ((float*)C)[co] = v;
                else         ((u16*)C)[co] = f2b(v);
            }
        }
    }
}

// ---------------------------------------------------------------------------
// S-with-exp GEMM (z over group): P = exp(clamp(q2 @ kn^T)), den += row sums.
// (scale already folded into q2.) 2-phase 32KB dbuf; LDS-transpose epilogue.
__global__ __launch_bounds__(256) void gemm_exp(
    const u16* __restrict__ A, const u16* __restrict__ WT,
    u16* __restrict__ P, float* __restrict__ den,
    int K, int lda, int ldb, int ldc,
    long long zsB, long long zsP)
{
    __shared__ u16 shmem[16384];
    const int tid = threadIdx.x;
    const int wv = tid >> 6, lane = tid & 63;
    const int lr = lane & 15, lq = lane >> 4;
    int bx = blockIdx.x, by = blockIdx.y, bz = blockIdx.z;
    xcd_remap(bx, by, bz);
    const int m0 = bx * 128;
    const int n0 = by * 128;
    const u16* Bz = WT + bz * zsB;
    u16* Pz = P + bz * zsP;
    float* dz = den + bz * 512;

    floatx4 acc[2][8];
#pragma unroll
    for (int i = 0; i < 2; ++i)
#pragma unroll
        for (int j = 0; j < 8; ++j)
            acc[i][j] = (floatx4){0.f, 0.f, 0.f, 0.f};

    MFMA_TILE_DBUF(A, Bz, lda, ldb, 0, K)

    u16* sh = shmem;                      // 64 x 136 u16 scratch
    float srow[2][4] = {};
#pragma unroll
    for (int ms = 0; ms < 2; ++ms) {
        __syncthreads();
#pragma unroll
        for (int ns = 0; ns < 8; ++ns)
#pragma unroll
            for (int r = 0; r < 4; ++r) {
                float l = acc[ms][ns][r];
                l = fminf(fmaxf(l, -60.f), 60.f);
                float p = __expf(l);
                srow[ms][r] += p;
                int row = wv * 16 + lq * 4 + r;
                int col = (ns * 16 + lr) ^ (((row >> 3) & 1) << 3);
                sh[row * 136 + col] = f2b(p);
            }
        __syncthreads();
#pragma unroll
        for (int j = 0; j < 4; ++j) {
            int idx = j * 256 + tid;
            int rl = idx >> 4, ch = idx & 15;
            int m = m0 + ((rl >> 4) << 5) + ms * 16 + (rl & 15);
            int src = rl * 136 + ((ch * 8) ^ ((((rl >> 3) & 1)) << 3));
            *(uint4*)&Pz[(long long)m * ldc + n0 + ch * 8] =
                *(const uint4*)&sh[src];
        }
    }
#pragma unroll
    for (int ms = 0; ms < 2; ++ms)
#pragma unroll
        for (int r = 0; r < 4; ++r) {
            float s = srow[ms][r];
            s += __shfl_xor(s, 1, 64);
            s += __shfl_xor(s, 2, 64);
            s += __shfl_xor(s, 4, 64);
            s += __shfl_xor(s, 8, 64);
            if (lr == 0)
                atomicAdd(&dz[m0 + wv * 32 + ms * 16 + lq * 4 + r], s);
        }
}

// ---------------------------------------------------------------------------
// Split-K PV over group: z = g*SPLIT + sp, chunk = 8192/SPLIT keys. 128-tile.
// B = knT (kn transposed), so part = (P @ kn) / den  (bf16).
__global__ __launch_bounds__(256) void gemm_pv(
    const u16* __restrict__ P, const u16* __restrict__ KT,
    const float* __restrict__ den, u16* __restrict__ part, int SPLIT)
{
    __shared__ u16 shmem[24576];
    const int tid = threadIdx.x;
    const int wv = tid >> 6, lane = tid & 63;
    const int lr = lane & 15, lq = lane >> 4;
    int bx = blockIdx.x, by = blockIdx.y, bz = blockIdx.z;
    xcd_remap(bx, by, bz);
    const int m0 = bx * 128;
    const int n0 = by * 128;
    const int g = bz / SPLIT, sp = bz - g * SPLIT;
    const int chunk = 8192 / SPLIT;
    const u16* Az = P + (long long)g * 512 * 8192;
    const u16* Bz = KT + (long long)g * 384 * 8192;
    const float* dg = den + g * 512;

    floatx4 acc[2][8];
#pragma unroll
    for (int i = 0; i < 2; ++i)
#pragma unroll
        for (int j = 0; j < 8; ++j)
            acc[i][j] = (floatx4){0.f, 0.f, 0.f, 0.f};

    MFMA_TILE_PIPE(Az, Bz, 8192, 8192, sp * chunk, sp * chunk + chunk)

    u16* pz = part + (long long)bz * 512 * 384;
#pragma unroll
    for (int ms = 0; ms < 2; ++ms)
#pragma unroll
        for (int r = 0; r < 4; ++r) {
            int m = m0 + wv * 32 + ms * 16 + lq * 4 + r;
            float inv = 1.0f / dg[m];
#pragma unroll
            for (int ns = 0; ns < 8; ++ns) {
                int col = n0 + ns * 16 + lr;
                pz[(long long)m * 384 + col] = f2b(acc[ms][ns][r] * inv);
            }
        }
}

// ---------------------------------------------------------------------------
// PV reduce over group: ao[g][q][d] = sum_sp part[g*SPLIT+sp][q][d]
__global__ __launch_bounds__(256) void pv_reduce_kernel(
    const u16* __restrict__ part, u16* __restrict__ AO, int SPLIT)
{
    int idx = blockIdx.x * 256 + threadIdx.x;   // G*512*96 threads
    int q = idx / 96, j = (idx - q * 96) * 4;   // q in [0, G*512)
    int g = q >> 9, ql = q & 511;
    const u16* base = part + ((long long)g * SPLIT * 512 + ql) * 384 + j;
    float4 s = make_float4(0.f, 0.f, 0.f, 0.f);
    for (int sp = 0; sp < SPLIT; ++sp) {
        uint2 v = *(const uint2*)(base + (long long)sp * 512 * 384);
        s.x += b2f((u16)(v.x & 0xffff));
        s.y += b2f((u16)(v.x >> 16));
        s.z += b2f((u16)(v.y & 0xffff));
        s.w += b2f((u16)(v.y >> 16));
    }
    stb4(AO + (long long)q * 384 + j, s);
}

// ---------------------------------------------------------------------------
// FF1 + GEGLU fused: gl = a * gelu(g). 128x(64+64) tile, 3-buffer pipeline.
__global__ __launch_bounds__(256) void gemm_ff1_geglu(
    const u16* __restrict__ A, const u16* __restrict__ WT,
    const float* __restrict__ bias, u16* __restrict__ C,
    int K, int lda, int ldb, int ldc)
{
    __shared__ u16 shmem[24576];
    const int tid = threadIdx.x;
    const int wv = tid >> 6, lane = tid & 63;
    const int lr = lane & 15, lq = lane >> 4;
    int bx = blockIdx.x, by = blockIdx.y, bz = blockIdx.z;
    xcd_remap_yf(bx, by, bz);
    const int m0 = bx * 128;
    const int n0 = by * 64;
    const int rlo = lane >> 2, c8 = (lane & 3) * 8;

    floatx4 accA[2][4], accG[2][4];
#pragma unroll
    for (int i = 0; i < 2; ++i)
#pragma unroll
        for (int j = 0; j < 4; ++j) {
            accA[i][j] = (floatx4){0.f, 0.f, 0.f, 0.f};
            accG[i][j] = (floatx4){0.f, 0.f, 0.f, 0.f};
        }

#define STAGE_FF(bufi, kk)                                                     \
    { u16* asd = shmem + (bufi) * 4096;                                        \
      u16* bsd = shmem + 12288 + (bufi) * 4096;                                \
      gl2lds16(asd + (wv * 32) * 32,                                           \
          A + (long long)(m0 + wv * 32 + rlo) * lda + (kk) + c8);              \
      gl2lds16(asd + (wv * 32 + 16) * 32,                                      \
          A + (long long)(m0 + wv * 32 + 16 + rlo) * lda + (kk) + c8);         \
      int r0 = wv * 32 + rlo, r1 = r0 + 16;                                    \
      int wrow0 = (r0 < 64) ? (n0 + r0) : (1536 + n0 + r0 - 64);               \
      int wrow1 = (r1 < 64) ? (n0 + r1) : (1536 + n0 + r1 - 64);               \
      gl2lds16(bsd + (wv * 32) * 32, WT + (long long)wrow0 * ldb + (kk) + c8); \
      gl2lds16(bsd + (wv * 32 + 16) * 32, WT + (long long)wrow1 * ldb + (kk) + c8); }

    const int T = K >> 5;
    STAGE_FF(0, 0)
    STAGE_FF(1, 32)
    int cur = 0;
    for (int t = 0; t < T; ++t) {
        if (t + 1 < T) { asm volatile("s_waitcnt vmcnt(4)" ::: "memory"); }
        else           { asm volatile("s_waitcnt vmcnt(0)" ::: "memory"); }
        __builtin_amdgcn_s_barrier();
        if (t + 2 < T) {
            int stg = (cur == 0) ? 2 : cur - 1;
            STAGE_FF(stg, (t + 2) * 32)
        }
        const u16* As_ = shmem + cur * 4096;
        const u16* Bs_ = shmem + 12288 + cur * 4096;
        bf16x8 a0 = *(const bf16x8*)&As_[(wv * 32 + lr) * 32 + lq * 8];
        bf16x8 a1 = *(const bf16x8*)&As_[(wv * 32 + 16 + lr) * 32 + lq * 8];
#pragma unroll
        for (int ns = 0; ns < 4; ++ns) {
            bf16x8 bA = *(const bf16x8*)&Bs_[(ns * 16 + lr) * 32 + lq * 8];
            bf16x8 bG = *(const bf16x8*)&Bs_[((64 + ns * 16) + lr) * 32 + lq * 8];
            accA[0][ns] = __builtin_amdgcn_mfma_f32_16x16x32_bf16(a0, bA, accA[0][ns], 0, 0, 0);
            accA[1][ns] = __builtin_amdgcn_mfma_f32_16x16x32_bf16(a1, bA, accA[1][ns], 0, 0, 0);
            accG[0][ns] = __builtin_amdgcn_mfma_f32_16x16x32_bf16(a0, bG, accG[0][ns], 0, 0, 0);
            accG[1][ns] = __builtin_amdgcn_mfma_f32_16x16x32_bf16(a1, bG, accG[1][ns], 0, 0, 0);
        }
        cur = (cur == 2) ? 0 : cur + 1;
    }
#undef STAGE_FF

    float ba[4], bg[4];
#pragma unroll
    for (int ns = 0; ns < 4; ++ns) {
        ba[ns] = bias[n0 + ns * 16 + lr];
        bg[ns] = bias[1536 + n0 + ns * 16 + lr];
    }
#pragma unroll
    for (int ms = 0; ms < 2; ++ms)
#pragma unroll
        for (int r = 0; r < 4; ++r) {
            int m = m0 + wv * 32 + ms * 16 + lq * 4 + r;
#pragma unroll
            for (int ns = 0; ns < 4; ++ns) {
                int col = n0 + ns * 16 + lr;
                float a = accA[ms][ns][r] + ba[ns];
                float g = accG[ms][ns][r] + bg[ns];
                float v = a * 0.5f * g * (1.0f + erff(g * 0.70710678118654752f));
                C[(long long)m * ldc + col] = f2b(v);
            }
        }
}

// ---------------------------------------------------------------------------
extern "C" void kernel_launch(void* const* d_in, const int* in_sizes, int n_in,
                              void* d_out, int out_size, void* d_ws, size_t ws_size,
                              hipStream_t stream) {
    const float* x     = (const float*)d_in[0];
    const float* w0    = (const float*)d_in[1];
    const float* b0    = (const float*)d_in[2];
    const float* w1    = (const float*)d_in[3];
    const float* b1    = (const float*)d_in[4];
    const float* w2    = (const float*)d_in[5];
    const float* b2    = (const float*)d_in[6];
    const float* w3    = (const float*)d_in[7];
    const float* b3    = (const float*)d_in[8];
    const float* query = (const float*)d_in[9];
    const float* lnqg  = (const float*)d_in[10];
    const float* lnqb  = (const float*)d_in[11];
    const float* lncg  = (const float*)d_in[12];
    const float* lncb  = (const float*)d_in[13];
    const float* wq    = (const float*)d_in[14];
    const float* wkv   = (const float*)d_in[15];
    const float* wo    = (const float*)d_in[16];
    const float* bo    = (const float*)d_in[17];
    const float* lnfg  = (const float*)d_in[18];
    const float* lnfb  = (const float*)d_in[19];
    const float* ffw1  = (const float*)d_in[20];
    const float* ffb1  = (const float*)d_in[21];
    const float* ffw2  = (const float*)d_in[22];
    const float* ffb2  = (const float*)d_in[23];
    float* out = (float*)d_out;
    char* wsb = (char*)d_ws;

    // ---- group size selection from ws_size (part fixed at 64 slots) ----
    auto need = [](int G) -> size_t {
        return (size_t)G * (3LL * 6291456 + 8388608)   // bufA,bufB,knT,P
             + 25165824                                // part (64 bf16 slots)
             + 6291456                                 // ao_all
             + 3 * 393216 + 32768                      // qn, qb, q2, den
             + 5898240;                                // weight pool
    };
    int G = 2;
    if      (ws_size >= need(16)) G = 16;
    else if (ws_size >= need(8))  G = 8;
    else if (ws_size >= need(4))  G = 4;
    const int SPLIT = 64 / G;

    long long off = 0;
    u16*   bufA   = (u16*)(wsb + off); off += (long long)G * 6291456;
    u16*   bufB   = (u16*)(wsb + off); off += (long long)G * 6291456;
    u16*   knT    = (u16*)(wsb + off); off += (long long)G * 6291456;
    u16*   Pb     = (u16*)(wsb + off); off += (long long)G * 8388608;
    u16*   part   = (u16*)(wsb + off); off += 25165824;
    u16*   ao_all = (u16*)(wsb + off); off += 6291456;
    u16*   qn     = (u16*)(wsb + off); off += 393216;
    u16*   qb     = (u16*)(wsb + off); off += 393216;
    u16*   q2     = (u16*)(wsb + off); off += 393216;
    float* den    = (float*)(wsb + off); off += 32768;
    u16*   w1T    = (u16*)(wsb + off); off += 294912;
    u16*   w2T    = (u16*)(wsb + off); off += 294912;
    u16*   w3T    = (u16*)(wsb + off); off += 294912;
    u16*   wqT    = (u16*)(wsb + off); off += 294912;
    u16*   woT    = (u16*)(wsb + off); off += 294912;
    u16*   ffw1T  = (u16*)(wsb + off); off += 2359296;
    u16*   ffw2T  = (u16*)(wsb + off); off += 1179648;
    u16*   wkdir  = (u16*)(wsb + off); off += 294912;   // wk natural layout
    u16*   wvdir  = (u16*)(wsb + off); off += 294912;   // wv natural layout
    u16*   wvoT   = (u16*)(wsb + off); off += 294912;   // (wv wo)^T
    // phase-2 overlays (bufA/bufB/knT region is dead by then)
    u16*   x1_all = (u16*)(wsb + 0);
    u16*   f0_all = (u16*)(wsb + 6291456);
    u16*   gl_all = (u16*)(wsb + 12582912);

    const int FULLMASK = 0x3FFFFFFF;

    // ---- setup ----
    wconv_all<<<10944, 256, 0, stream>>>(w1, w2, w3, wq, wkv, wo, ffw1, ffw2,
        w1T, w2T, w3T, wqT, woT, ffw1T, ffw2T, wkdir, wvdir);
    hipMemsetAsync(den, 0, 16 * 512 * sizeof(float), stream);
    ln_kernel<1><<<128, 256, 0, stream>>>(query, lnqg, lnqb, qn, 512);
    gemm_mfma<0, 0><<<dim3(4, 3), 256, 0, stream>>>(qn, wqT, nullptr, nullptr, qb,
        512, 384, 384, 384, 384, 384, 0, 1.f, 0, FULLMASK, 0, 0, 0);
    // q2 = scale * (qb @ wk^T): folds the K-projection into the query side.
    gemm_mfma<0, 0><<<dim3(4, 3), 256, 0, stream>>>(qb, wkdir, nullptr, nullptr, q2,
        512, 384, 384, 384, 384, 384, 0, 0.05103103630798288f, 0, FULLMASK, 0, 0, 0);
    // wvoT[o][d] = sum_c woT[o][c] * wv[d][c] = ((wv)(wo))^T
    gemm_mfma<0, 0><<<dim3(3, 3), 256, 0, stream>>>(woT, wvdir, nullptr, nullptr, wvoT,
        384, 384, 384, 384, 384, 384, 0, 1.f, 0, FULLMASK, 0, 0, 0);

    // ---- phase 1: groups of G batches ----
    const int MG = G * 8192;
    for (int base = 0; base < 16; base += G) {
        const float* xg = x + (long long)base * 24576;

        layer0_kernel<<<G * 3072, 256, 0, stream>>>(xg, w0, b0, bufA, G * 786432);
        gemm_mfma<0, 0><<<dim3(MG / 128, 3), 256, 0, stream>>>(bufA, w1T, b1, nullptr, bufB,
            MG, 384, 384, 384, 384, 384, 0, 1.f, 1, FULLMASK, 0, 0, 0);
        gemm_mfma<0, 0><<<dim3(MG / 128, 3), 256, 0, stream>>>(bufB, w2T, b2, nullptr, bufA,
            MG, 384, 384, 384, 384, 384, 0, 1.f, 1, FULLMASK, 0, 0, 0);
        gemm_mfma<0, 0><<<dim3(MG / 128, 3), 256, 0, stream>>>(bufA, w3T, b3, nullptr, bufB,
            MG, 384, 384, 384, 384, 384, 0, 1.f, 0, FULLMASK, 0, 0, 0);   // ctx -> bufB
        // kn (natural -> bufA) AND kn^T (-> knT) in one LayerNorm pass
        ln_tr_kernel<<<MG / 64, 256, 0, stream>>>(bufB, lncg, lncb, bufA, knT);
        // P_g = exp(q2 @ kn_g^T)  (kn consumed directly; scale in q2)
        gemm_exp<<<dim3(4, 64, G), 256, 0, stream>>>(q2, bufA, Pb, den + base * 512,
            384, 384, 384, 8192, 8192LL * 384, 512LL * 8192);
        // PV split-K partials: part = (P @ kn)/den via knT  (z = g*SPLIT + sp)
        gemm_pv<<<dim3(4, 3, G * SPLIT), 256, 0, stream>>>(Pb, knT, den + base * 512,
            part, SPLIT);
        // reduce -> ao_all[base..base+G)
        pv_reduce_kernel<<<G * 192, 256, 0, stream>>>(part,
            ao_all + (long long)base * 196608, SPLIT);
    }

    // ---- phase 2: batched across all 16 ----
    // x1 = ao2 @ (wv wo) + bo + lq   (V-projection folded into wvo)
    gemm_mfma<1, 0><<<dim3(64, 3), 256, 0, stream>>>(ao_all, wvoT, bo, query, x1_all,
        8192, 384, 384, 384, 384, 384, 384, 1.f, 0, 511, 0, 0, 0);
    ln_kernel<0><<<2048, 256, 0, stream>>>(x1_all, lnfg, lnfb, f0_all, 8192);
    gemm_ff1_geglu<<<dim3(64, 24), 256, 0, stream>>>(f0_all, ffw1T, ffb1, gl_all,
        384, 384, 384, 1536);
    gemm_mfma<0, 1><<<dim3(64, 3), 256, 0, stream>>>(gl_all, ffw2T, ffb2, x1_all, out,
        8192, 384, 1536, 1536, 1536, 384, 384, 1.f, 0, FULLMASK, 0, 0, 0);
}

// Round 15
// 754.787 us; speedup vs baseline: 1.1380x; 1.0141x over previous
//
#include <hip/hip_runtime.h>
#include <math.h>

// B=16, N=8192, L=512, D=384, FF=1536. INPUTS fp32, OUTPUT fp32.
// Round-14 configuration (best verified: 765us) + T5 s_setprio around the
// MFMA cluster of the counted-vmcnt 3-buffer pipe (structure-conditional
// catalog technique; exp's lockstep 2-phase loop left as control).
// Algebraic folds: q2 = scale*qb@wk^T (no K GEMM); wvo = wv@wo (no V GEMM,
// PV consumes kn^T from the dual-output ctx LayerNorm).

typedef unsigned short u16;
typedef unsigned int   u32;
typedef __bf16 bf16_t;
typedef bf16_t bf16x8 __attribute__((ext_vector_type(8)));
typedef float  floatx4 __attribute__((ext_vector_type(4)));

__device__ __forceinline__ float b2f(u16 v) {
    return __uint_as_float(((u32)v) << 16);
}
__device__ __forceinline__ u16 f2b(float f) {
    bf16_t h = (bf16_t)f;
    return __builtin_bit_cast(u16, h);
}
__device__ __forceinline__ void stb4(u16* p, float4 f) {
    uint2 v;
    v.x = (u32)f2b(f.x) | ((u32)f2b(f.y) << 16);
    v.y = (u32)f2b(f.z) | ((u32)f2b(f.w) << 16);
    *(uint2*)p = v;
}

// async global->LDS, 16B per lane; LDS dest is wave-uniform base + lane*16.
__device__ __forceinline__ void gl2lds16(u16* lds, const u16* g) {
    __builtin_amdgcn_global_load_lds(
        (const __attribute__((address_space(1))) void*)g,
        (__attribute__((address_space(3))) void*)lds, 16, 0, 0);
}

// Bijective XCD-chunked remap, x-fastest linearization. Identity if nb%8.
__device__ __forceinline__ void xcd_remap(int& bx, int& by, int& bz) {
    int gx = gridDim.x, gy = gridDim.y, gz = gridDim.z;
    int nb = gx * gy * gz;
    int p = bx + gx * (by + gy * bz);
    if ((nb & 7) == 0) {
        int chunk = nb >> 3;
        p = (p & 7) * chunk + (p >> 3);
    }
    bx = p % gx;
    int t = p / gx;
    by = t % gy;
    bz = t / gy;
}

// y-fastest variant: blocks sharing an A-panel are consecutive -> colocated.
__device__ __forceinline__ void xcd_remap_yf(int& bx, int& by, int& bz) {
    int gx = gridDim.x, gy = gridDim.y, gz = gridDim.z;
    int nb = gx * gy * gz;
    int p = by + gy * (bx + gx * bz);
    if ((nb & 7) == 0) {
        int chunk = nb >> 3;
        p = (p & 7) * chunk + (p >> 3);
    }
    by = p % gy;
    int t = p / gy;
    bx = t % gx;
    bz = t / gx;
}

// ---------------------------------------------------------------------------
// All-weights convert in ONE launch. Transposed segments: W [Kd][Nd] ->
// WT bf16 [Nd][Kd]. Natural-layout extracts: wkdir = wkv[:, :384] rows,
// wvdir = wkv[:, 384:768] rows.
__global__ __launch_bounds__(256) void wconv_all(
    const float* __restrict__ w1, const float* __restrict__ w2,
    const float* __restrict__ w3, const float* __restrict__ wq,
    const float* __restrict__ wkv, const float* __restrict__ wo,
    const float* __restrict__ ffw1, const float* __restrict__ ffw2,
    u16* __restrict__ d1, u16* __restrict__ d2, u16* __restrict__ d3,
    u16* __restrict__ dq, u16* __restrict__ dо,
    u16* __restrict__ dffw1, u16* __restrict__ dffw2,
    u16* __restrict__ dwkd, u16* __restrict__ dwvd)
{
    int idx = blockIdx.x * 256 + threadIdx.x;
    if (idx >= 2801664) return;
    if (idx >= 2654208) {                 // wvdir: wkv[d][384+c]
        int local = idx - 2654208;
        int dd = local / 384, c = local - dd * 384;
        dwvd[local] = f2b(wkv[(long long)dd * 768 + 384 + c]);
        return;
    }
    if (idx >= 2506752) {                 // wkdir: wkv[e][d], d<384
        int local = idx - 2506752;
        int e = local / 384, d = local - e * 384;
        dwkd[local] = f2b(wkv[(long long)e * 768 + d]);
        return;
    }
    const float* W; u16* WT; int Kd, Nd, local;
    if      (idx <  147456) { W=w1;   WT=d1;    Kd=384;  Nd=384;  local=idx; }
    else if (idx <  294912) { W=w2;   WT=d2;    Kd=384;  Nd=384;  local=idx-147456; }
    else if (idx <  442368) { W=w3;   WT=d3;    Kd=384;  Nd=384;  local=idx-294912; }
    else if (idx <  589824) { W=wq;   WT=dq;    Kd=384;  Nd=384;  local=idx-442368; }
    else if (idx <  737280) { W=wo;   WT=dо;    Kd=384;  Nd=384;  local=idx-589824; }
    else if (idx < 1916928) { W=ffw1; WT=dffw1; Kd=384;  Nd=3072; local=idx-737280; }
    else                    { W=ffw2; WT=dffw2; Kd=1536; Nd=384;  local=idx-1916928; }
    int n = local / Kd, k = local - n * Kd;
    WT[local] = f2b(W[(long long)k * Nd + n]);
}

// ---------------------------------------------------------------------------
// Layer 0: h = relu(x @ w0 + b0); x fp32 [M][3], out bf16
__global__ __launch_bounds__(256) void layer0_kernel(
    const float* __restrict__ X, const float* __restrict__ W0,
    const float* __restrict__ B0, u16* __restrict__ H, int total4)
{
    int idx = blockIdx.x * 256 + threadIdx.x;
    if (idx >= total4) return;
    int e = idx * 4;
    int m = e / 384;
    int j = e - m * 384;
    float x0 = X[m * 3 + 0], x1 = X[m * 3 + 1], x2 = X[m * 3 + 2];
    float4 w0 = *(const float4*)(W0 + j);
    float4 w1 = *(const float4*)(W0 + 384 + j);
    float4 w2 = *(const float4*)(W0 + 768 + j);
    float4 bb = *(const float4*)(B0 + j);
    float4 v;
    v.x = fmaxf(bb.x + x0 * w0.x + x1 * w1.x + x2 * w2.x, 0.f);
    v.y = fmaxf(bb.y + x0 * w0.y + x1 * w1.y + x2 * w2.y, 0.f);
    v.z = fmaxf(bb.z + x0 * w0.z + x1 * w1.z + x2 * w2.z, 0.f);
    v.w = fmaxf(bb.w + x0 * w0.w + x1 * w1.w + x2 * w2.w, 0.f);
    stb4(H + e, v);
}

// ---------------------------------------------------------------------------
// LayerNorm; input fp32 (IN_F32=1) or bf16; g,b fp32; out bf16. 4 rows/block.
template<int IN_F32>
__global__ __launch_bounds__(256) void ln_kernel(
    const void* __restrict__ Xv, const float* __restrict__ g,
    const float* __restrict__ b, u16* __restrict__ Y, int rows)
{
    int w = threadIdx.x >> 6, lane = threadIdx.x & 63;
    int row = blockIdx.x * 4 + w;
    if (row >= rows) return;
    float v[6];
    float s = 0.f, ss = 0.f;
#pragma unroll
    for (int i = 0; i < 6; ++i) {
        int c = i * 64 + lane;
        v[i] = IN_F32 ? ((const float*)Xv)[(long long)row * 384 + c]
                      : b2f(((const u16*)Xv)[(long long)row * 384 + c]);
        s += v[i]; ss += v[i] * v[i];
    }
#pragma unroll
    for (int m = 32; m; m >>= 1) {
        s  += __shfl_xor(s, m, 64);
        ss += __shfl_xor(ss, m, 64);
    }
    float mean = s * (1.0f / 384.0f);
    float var  = ss * (1.0f / 384.0f) - mean * mean;
    float rs = rsqrtf(fmaxf(var, 0.f) + 1e-5f);
    u16* yr = Y + (long long)row * 384;
#pragma unroll
    for (int i = 0; i < 6; ++i) {
        int c = i * 64 + lane;
        yr[c] = f2b((v[i] - mean) * rs * g[c] + b[c]);
    }
}

// ---------------------------------------------------------------------------
// LayerNorm with dual output: Y [MG][384] natural AND YT [G][384][8192]
// transposed (for the PV GEMM's B operand). 64 rows/block, 4 waves x 16 rows;
// LDS transpose with pad-72 (16B-aligned stripes). bf16 in/out.
__global__ __launch_bounds__(256) void ln_tr_kernel(
    const u16* __restrict__ Xv, const float* __restrict__ g,
    const float* __restrict__ b, u16* __restrict__ Y, u16* __restrict__ YT)
{
    __shared__ u16 tr[384 * 72];          // 55296 B
    int w = threadIdx.x >> 6, lane = threadIdx.x & 63;
    int row0 = blockIdx.x * 64;
    for (int rr = 0; rr < 16; ++rr) {
        int jl = w * 16 + rr;
        long long row = row0 + jl;
        float v[6];
        float s = 0.f, ss = 0.f;
#pragma unroll
        for (int i = 0; i < 6; ++i) {
            int c = i * 64 + lane;
            v[i] = b2f(Xv[row * 384 + c]);
            s += v[i]; ss += v[i] * v[i];
        }
#pragma unroll
        for (int m = 32; m; m >>= 1) {
            s  += __shfl_xor(s, m, 64);
            ss += __shfl_xor(ss, m, 64);
        }
        float mean = s * (1.0f / 384.0f);
        float var  = ss * (1.0f / 384.0f) - mean * mean;
        float rs = rsqrtf(fmaxf(var, 0.f) + 1e-5f);
        u16* yr = Y + row * 384;
#pragma unroll
        for (int i = 0; i < 6; ++i) {
            int c = i * 64 + lane;
            u16 val = f2b((v[i] - mean) * rs * g[c] + b[c]);
            yr[c] = val;
            tr[c * 72 + jl] = val;
        }
    }
    __syncthreads();
    // transposed write-out: row0 is 64-aligned within a batch (8192 rows).
    int gb = row0 >> 13;
    int jloc = row0 & 8191;
    u16* yt = YT + (long long)gb * 384 * 8192 + jloc;
    for (int e = threadIdx.x; e < 384; e += 256) {
        const u16* src = &tr[e * 72];
        u16* dst = yt + (long long)e * 8192;
#pragma unroll
        for (int q = 0; q < 8; ++q)
            *(uint4*)(dst + q * 8) = *(const uint4*)(src + q * 8);
    }
}

// ---------------------------------------------------------------------------
// 3-buffer pipelined 128x128 K-loop. As_i @ i*4096, Bs_i @ 12288+i*4096
// (48KB). Counted vmcnt keeps 2 K-steps in flight; T5 setprio(1) wraps the
// MFMA cluster (role-split waves -> scheduler favors MFMA-entering waves).
#define STAGE_AB3(bufi, kk)                                                    \
    { u16* asd_ = shmem + (bufi) * 4096;                                       \
      u16* bsd_ = shmem + 12288 + (bufi) * 4096;                               \
      gl2lds16(asd_ + (wv * 32) * 32,                                          \
          aptr_ + (long long)(m0 + wv * 32 + rlo_) * lda_ + (kk) + c8_);       \
      gl2lds16(asd_ + (wv * 32 + 16) * 32,                                     \
          aptr_ + (long long)(m0 + wv * 32 + 16 + rlo_) * lda_ + (kk) + c8_);  \
      gl2lds16(bsd_ + (wv * 32) * 32,                                          \
          bptr_ + (long long)(n0 + wv * 32 + rlo_) * ldb_ + (kk) + c8_);       \
      gl2lds16(bsd_ + (wv * 32 + 16) * 32,                                     \
          bptr_ + (long long)(n0 + wv * 32 + 16 + rlo_) * ldb_ + (kk) + c8_); }

#define MFMA_TILE_PIPE(Aptr, Bptr, LDA, LDB, K0, K1)                           \
    {                                                                          \
        const u16* aptr_ = (Aptr); const u16* bptr_ = (Bptr);                  \
        const long long lda_ = (LDA), ldb_ = (LDB);                            \
        const int rlo_ = lane >> 2, c8_ = (lane & 3) * 8;                      \
        const int T_ = ((K1) - (K0)) >> 5;                                     \
        STAGE_AB3(0, (K0))                                                     \
        STAGE_AB3(1, (K0) + 32)                                                \
        int cur = 0;                                                           \
        for (int t = 0; t < T_; ++t) {                                         \
            if (t + 1 < T_) { asm volatile("s_waitcnt vmcnt(4)" ::: "memory"); } \
            else            { asm volatile("s_waitcnt vmcnt(0)" ::: "memory"); } \
            __builtin_amdgcn_s_barrier();                                      \
            if (t + 2 < T_) {                                                  \
                int stg = (cur == 0) ? 2 : cur - 1;                            \
                STAGE_AB3(stg, (K0) + (t + 2) * 32)                            \
            }                                                                  \
            const u16* As_ = shmem + cur * 4096;                               \
            const u16* Bs_ = shmem + 12288 + cur * 4096;                       \
            bf16x8 a0 = *(const bf16x8*)&As_[(wv * 32 + lr) * 32 + lq * 8];    \
            bf16x8 a1 = *(const bf16x8*)&As_[(wv * 32 + 16 + lr) * 32 + lq * 8]; \
            __builtin_amdgcn_s_setprio(1);                                     \
            _Pragma("unroll")                                                  \
            for (int ns = 0; ns < 8; ++ns) {                                   \
                bf16x8 b = *(const bf16x8*)&Bs_[(ns * 16 + lr) * 32 + lq * 8]; \
                acc[0][ns] = __builtin_amdgcn_mfma_f32_16x16x32_bf16(a0, b, acc[0][ns], 0, 0, 0); \
                acc[1][ns] = __builtin_amdgcn_mfma_f32_16x16x32_bf16(a1, b, acc[1][ns], 0, 0, 0); \
            }                                                                  \
            __builtin_amdgcn_s_setprio(0);                                     \
            cur = (cur == 2) ? 0 : cur + 1;                                    \
        }                                                                      \
    }

// 2-phase double-buffered loop (short-K, epilogue-heavy kernels; 32 KB LDS
// -> 5 blocks/CU). As0 @0, As1 @4096, Bs0 @8192, Bs1 @12288. (Control: no
// setprio here — lockstep barrier structure, T5 null per m190.)
#define STAGE_AB2(bufi, kk)                                                    \
    { u16* asd_ = shmem + (bufi) * 4096;                                       \
      u16* bsd_ = shmem + 8192 + (bufi) * 4096;                                \
      gl2lds16(asd_ + (wv * 32) * 32,                                          \
          aptr_ + (long long)(m0 + wv * 32 + rlo_) * lda_ + (kk) + c8_);       \
      gl2lds16(asd_ + (wv * 32 + 16) * 32,                                     \
          aptr_ + (long long)(m0 + wv * 32 + 16 + rlo_) * lda_ + (kk) + c8_);  \
      gl2lds16(bsd_ + (wv * 32) * 32,                                          \
          bptr_ + (long long)(n0 + wv * 32 + rlo_) * ldb_ + (kk) + c8_);       \
      gl2lds16(bsd_ + (wv * 32 + 16) * 32,                                     \
          bptr_ + (long long)(n0 + wv * 32 + 16 + rlo_) * ldb_ + (kk) + c8_); }

#define MFMA_TILE_DBUF(Aptr, Bptr, LDA, LDB, K0, K1)                           \
    {                                                                          \
        const u16* aptr_ = (Aptr); const u16* bptr_ = (Bptr);                  \
        const long long lda_ = (LDA), ldb_ = (LDB);                            \
        const int rlo_ = lane >> 2, c8_ = (lane & 3) * 8;                      \
        int cur = 0;                                                           \
        STAGE_AB2(0, (K0))                                                     \
        for (int k0 = (K0); k0 < (K1); k0 += 32) {                             \
            __syncthreads();                                                   \
            if (k0 + 32 < (K1)) STAGE_AB2(cur ^ 1, k0 + 32)                    \
            const u16* As_ = shmem + cur * 4096;                               \
            const u16* Bs_ = shmem + 8192 + cur * 4096;                        \
            bf16x8 a0 = *(const bf16x8*)&As_[(wv * 32 + lr) * 32 + lq * 8];    \
            bf16x8 a1 = *(const bf16x8*)&As_[(wv * 32 + 16 + lr) * 32 + lq * 8]; \
            _Pragma("unroll")                                                  \
            for (int ns = 0; ns < 8; ++ns) {                                   \
                bf16x8 b = *(const bf16x8*)&Bs_[(ns * 16 + lr) * 32 + lq * 8]; \
                acc[0][ns] = __builtin_amdgcn_mfma_f32_16x16x32_bf16(a0, b, acc[0][ns], 0, 0, 0); \
                acc[1][ns] = __builtin_amdgcn_mfma_f32_16x16x32_bf16(a1, b, acc[1][ns], 0, 0, 0); \
            }                                                                  \
            cur ^= 1;                                                          \
        }                                                                      \
    }

// Generic GEMM with z-strides: C = act(scale*A@WT^T + bias) + res.
template<int RES_F32, int OUT_F32>
__global__ __launch_bounds__(256) void gemm_mfma(
    const u16* __restrict__ A, const u16* __restrict__ WT,
    const float* __restrict__ bias, const void* __restrict__ res,
    void* __restrict__ C,
    int M, int N, int K, int lda, int ldb, int ldc, int ldres,
    float scale, int relu, int resmask,
    long long zsA, long long zsB, long long zsC)
{
    __shared__ u16 shmem[24576];
    const int tid = threadIdx.x;
    const int wv = tid >> 6, lane = tid & 63;
    const int lr = lane & 15, lq = lane >> 4;
    int bx = blockIdx.x, by = blockIdx.y, bz = blockIdx.z;
    xcd_remap_yf(bx, by, bz);
    const int m0 = bx * 128;
    const int n0 = by * 128;
    const u16* Az = A + bz * zsA;
    const u16* Bz = WT + bz * zsB;
    const long long czoff = bz * zsC;

    floatx4 acc[2][8];
#pragma unroll
    for (int i = 0; i < 2; ++i)
#pragma unroll
        for (int j = 0; j < 8; ++j)
            acc[i][j] = (floatx4){0.f, 0.f, 0.f, 0.f};

    MFMA_TILE_PIPE(Az, Bz, lda, ldb, 0, K)

    float bi[8];
#pragma unroll
    for (int ns = 0; ns < 8; ++ns)
        bi[ns] = bias ? bias[n0 + ns * 16 + lr] : 0.f;

#pragma unroll
    for (int ms = 0; ms < 2; ++ms) {
#pragma unroll
        for (int r = 0; r < 4; ++r) {
            int m = m0 + wv * 32 + ms * 16 + lq * 4 + r;
#pragma unroll
            for (int ns = 0; ns < 8; ++ns) {
                int col = n0 + ns * 16 + lr;
                float v = acc[ms][ns][r] * scale + bi[ns];
                if (relu) v = fmaxf(v, 0.f);
                if (res) {
                    long long ro = (long long)(m & resmask) * ldres + col;
                    v += RES_F32 ? ((const float*)res)[ro]
                                 : b2f(((const u16*)res)[ro]);
                }
                long long co = czoff + (long long)m * ldc + col;
                if (OUT_F32) ((float*)C)[co] = v;
                else         ((u16*)C)[co] = f2b(v);
            }
        }
    }
}

// ---------------------------------------------------------------------------
// S-with-exp GEMM (z over group): P = exp(clamp(q2 @ kn^T)), den += row sums.
// (scale already folded into q2.) 2-phase 32KB dbuf; LDS-transpose epilogue.
__global__ __launch_bounds__(256) void gemm_exp(
    const u16* __restrict__ A, const u16* __restrict__ WT,
    u16* __restrict__ P, float* __restrict__ den,
    int K, int lda, int ldb, int ldc,
    long long zsB, long long zsP)
{
    __shared__ u16 shmem[16384];
    const int tid = threadIdx.x;
    const int wv = tid >> 6, lane = tid & 63;
    const int lr = lane & 15, lq = lane >> 4;
    int bx = blockIdx.x, by = blockIdx.y, bz = blockIdx.z;
    xcd_remap(bx, by, bz);
    const int m0 = bx * 128;
    const int n0 = by * 128;
    const u16* Bz = WT + bz * zsB;
    u16* Pz = P + bz * zsP;
    float* dz = den + bz * 512;

    floatx4 acc[2][8];
#pragma unroll
    for (int i = 0; i < 2; ++i)
#pragma unroll
        for (int j = 0; j < 8; ++j)
            acc[i][j] = (floatx4){0.f, 0.f, 0.f, 0.f};

    MFMA_TILE_DBUF(A, Bz, lda, ldb, 0, K)

    u16* sh = shmem;                      // 64 x 136 u16 scratch
    float srow[2][4] = {};
#pragma unroll
    for (int ms = 0; ms < 2; ++ms) {
        __syncthreads();
#pragma unroll
        for (int ns = 0; ns < 8; ++ns)
#pragma unroll
            for (int r = 0; r < 4; ++r) {
                float l = acc[ms][ns][r];
                l = fminf(fmaxf(l, -60.f), 60.f);
                float p = __expf(l);
                srow[ms][r] += p;
                int row = wv * 16 + lq * 4 + r;
                int col = (ns * 16 + lr) ^ (((row >> 3) & 1) << 3);
                sh[row * 136 + col] = f2b(p);
            }
        __syncthreads();
#pragma unroll
        for (int j = 0; j < 4; ++j) {
            int idx = j * 256 + tid;
            int rl = idx >> 4, ch = idx & 15;
            int m = m0 + ((rl >> 4) << 5) + ms * 16 + (rl & 15);
            int src = rl * 136 + ((ch * 8) ^ ((((rl >> 3) & 1)) << 3));
            *(uint4*)&Pz[(long long)m * ldc + n0 + ch * 8] =
                *(const uint4*)&sh[src];
        }
    }
#pragma unroll
    for (int ms = 0; ms < 2; ++ms)
#pragma unroll
        for (int r = 0; r < 4; ++r) {
            float s = srow[ms][r];
            s += __shfl_xor(s, 1, 64);
            s += __shfl_xor(s, 2, 64);
            s += __shfl_xor(s, 4, 64);
            s += __shfl_xor(s, 8, 64);
            if (lr == 0)
                atomicAdd(&dz[m0 + wv * 32 + ms * 16 + lq * 4 + r], s);
        }
}

// ---------------------------------------------------------------------------
// Split-K PV over group: z = g*SPLIT + sp, chunk = 8192/SPLIT keys. 128-tile.
// B = knT (kn transposed), so part = (P @ kn) / den  (bf16).
__global__ __launch_bounds__(256) void gemm_pv(
    const u16* __restrict__ P, const u16* __restrict__ KT,
    const float* __restrict__ den, u16* __restrict__ part, int SPLIT)
{
    __shared__ u16 shmem[24576];
    const int tid = threadIdx.x;
    const int wv = tid >> 6, lane = tid & 63;
    const int lr = lane & 15, lq = lane >> 4;
    int bx = blockIdx.x, by = blockIdx.y, bz = blockIdx.z;
    xcd_remap(bx, by, bz);
    const int m0 = bx * 128;
    const int n0 = by * 128;
    const int g = bz / SPLIT, sp = bz - g * SPLIT;
    const int chunk = 8192 / SPLIT;
    const u16* Az = P + (long long)g * 512 * 8192;
    const u16* Bz = KT + (long long)g * 384 * 8192;
    const float* dg = den + g * 512;

    floatx4 acc[2][8];
#pragma unroll
    for (int i = 0; i < 2; ++i)
#pragma unroll
        for (int j = 0; j < 8; ++j)
            acc[i][j] = (floatx4){0.f, 0.f, 0.f, 0.f};

    MFMA_TILE_PIPE(Az, Bz, 8192, 8192, sp * chunk, sp * chunk + chunk)

    u16* pz = part + (long long)bz * 512 * 384;
#pragma unroll
    for (int ms = 0; ms < 2; ++ms)
#pragma unroll
        for (int r = 0; r < 4; ++r) {
            int m = m0 + wv * 32 + ms * 16 + lq * 4 + r;
            float inv = 1.0f / dg[m];
#pragma unroll
            for (int ns = 0; ns < 8; ++ns) {
                int col = n0 + ns * 16 + lr;
                pz[(long long)m * 384 + col] = f2b(acc[ms][ns][r] * inv);
            }
        }
}

// ---------------------------------------------------------------------------
// PV reduce over group: ao[g][q][d] = sum_sp part[g*SPLIT+sp][q][d]
__global__ __launch_bounds__(256) void pv_reduce_kernel(
    const u16* __restrict__ part, u16* __restrict__ AO, int SPLIT)
{
    int idx = blockIdx.x * 256 + threadIdx.x;   // G*512*96 threads
    int q = idx / 96, j = (idx - q * 96) * 4;   // q in [0, G*512)
    int g = q >> 9, ql = q & 511;
    const u16* base = part + ((long long)g * SPLIT * 512 + ql) * 384 + j;
    float4 s = make_float4(0.f, 0.f, 0.f, 0.f);
    for (int sp = 0; sp < SPLIT; ++sp) {
        uint2 v = *(const uint2*)(base + (long long)sp * 512 * 384);
        s.x += b2f((u16)(v.x & 0xffff));
        s.y += b2f((u16)(v.x >> 16));
        s.z += b2f((u16)(v.y & 0xffff));
        s.w += b2f((u16)(v.y >> 16));
    }
    stb4(AO + (long long)q * 384 + j, s);
}

// ---------------------------------------------------------------------------
// FF1 + GEGLU fused: gl = a * gelu(g). 128x(64+64) tile, 3-buffer pipeline
// with T5 setprio around the MFMA cluster.
__global__ __launch_bounds__(256) void gemm_ff1_geglu(
    const u16* __restrict__ A, const u16* __restrict__ WT,
    const float* __restrict__ bias, u16* __restrict__ C,
    int K, int lda, int ldb, int ldc)
{
    __shared__ u16 shmem[24576];
    const int tid = threadIdx.x;
    const int wv = tid >> 6, lane = tid & 63;
    const int lr = lane & 15, lq = lane >> 4;
    int bx = blockIdx.x, by = blockIdx.y, bz = blockIdx.z;
    xcd_remap_yf(bx, by, bz);
    const int m0 = bx * 128;
    const int n0 = by * 64;
    const int rlo = lane >> 2, c8 = (lane & 3) * 8;

    floatx4 accA[2][4], accG[2][4];
#pragma unroll
    for (int i = 0; i < 2; ++i)
#pragma unroll
        for (int j = 0; j < 4; ++j) {
            accA[i][j] = (floatx4){0.f, 0.f, 0.f, 0.f};
            accG[i][j] = (floatx4){0.f, 0.f, 0.f, 0.f};
        }

#define STAGE_FF(bufi, kk)                                                     \
    { u16* asd = shmem + (bufi) * 4096;                                        \
      u16* bsd = shmem + 12288 + (bufi) * 4096;                                \
      gl2lds16(asd + (wv * 32) * 32,                                           \
          A + (long long)(m0 + wv * 32 + rlo) * lda + (kk) + c8);              \
      gl2lds16(asd + (wv * 32 + 16) * 32,                                      \
          A + (long long)(m0 + wv * 32 + 16 + rlo) * lda + (kk) + c8);         \
      int r0 = wv * 32 + rlo, r1 = r0 + 16;                                    \
      int wrow0 = (r0 < 64) ? (n0 + r0) : (1536 + n0 + r0 - 64);               \
      int wrow1 = (r1 < 64) ? (n0 + r1) : (1536 + n0 + r1 - 64);               \
      gl2lds16(bsd + (wv * 32) * 32, WT + (long long)wrow0 * ldb + (kk) + c8); \
      gl2lds16(bsd + (wv * 32 + 16) * 32, WT + (long long)wrow1 * ldb + (kk) + c8); }

    const int T = K >> 5;
    STAGE_FF(0, 0)
    STAGE_FF(1, 32)
    int cur = 0;
    for (int t = 0; t < T; ++t) {
        if (t + 1 < T) { asm volatile("s_waitcnt vmcnt(4)" ::: "memory"); }
        else           { asm volatile("s_waitcnt vmcnt(0)" ::: "memory"); }
        __builtin_amdgcn_s_barrier();
        if (t + 2 < T) {
            int stg = (cur == 0) ? 2 : cur - 1;
            STAGE_FF(stg, (t + 2) * 32)
        }
        const u16* As_ = shmem + cur * 4096;
        const u16* Bs_ = shmem + 12288 + cur * 4096;
        bf16x8 a0 = *(const bf16x8*)&As_[(wv * 32 + lr) * 32 + lq * 8];
        bf16x8 a1 = *(const bf16x8*)&As_[(wv * 32 + 16 + lr) * 32 + lq * 8];
        __builtin_amdgcn_s_setprio(1);
#pragma unroll
        for (int ns = 0; ns < 4; ++ns) {
            bf16x8 bA = *(const bf16x8*)&Bs_[(ns * 16 + lr) * 32 + lq * 8];
            bf16x8 bG = *(const bf16x8*)&Bs_[((64 + ns * 16) + lr) * 32 + lq * 8];
            accA[0][ns] = __builtin_amdgcn_mfma_f32_16x16x32_bf16(a0, bA, accA[0][ns], 0, 0, 0);
            accA[1][ns] = __builtin_amdgcn_mfma_f32_16x16x32_bf16(a1, bA, accA[1][ns], 0, 0, 0);
            accG[0][ns] = __builtin_amdgcn_mfma_f32_16x16x32_bf16(a0, bG, accG[0][ns], 0, 0, 0);
            accG[1][ns] = __builtin_amdgcn_mfma_f32_16x16x32_bf16(a1, bG, accG[1][ns], 0, 0, 0);
        }
        __builtin_amdgcn_s_setprio(0);
        cur = (cur == 2) ? 0 : cur + 1;
    }
#undef STAGE_FF

    float ba[4], bg[4];
#pragma unroll
    for (int ns = 0; ns < 4; ++ns) {
        ba[ns] = bias[n0 + ns * 16 + lr];
        bg[ns] = bias[1536 + n0 + ns * 16 + lr];
    }
#pragma unroll
    for (int ms = 0; ms < 2; ++ms)
#pragma unroll
        for (int r = 0; r < 4; ++r) {
            int m = m0 + wv * 32 + ms * 16 + lq * 4 + r;
#pragma unroll
            for (int ns = 0; ns < 4; ++ns) {
                int col = n0 + ns * 16 + lr;
                float a = accA[ms][ns][r] + ba[ns];
                float g = accG[ms][ns][r] + bg[ns];
                float v = a * 0.5f * g * (1.0f + erff(g * 0.70710678118654752f));
                C[(long long)m * ldc + col] = f2b(v);
            }
        }
}

// ---------------------------------------------------------------------------
extern "C" void kernel_launch(void* const* d_in, const int* in_sizes, int n_in,
                              void* d_out, int out_size, void* d_ws, size_t ws_size,
                              hipStream_t stream) {
    const float* x     = (const float*)d_in[0];
    const float* w0    = (const float*)d_in[1];
    const float* b0    = (const float*)d_in[2];
    const float* w1    = (const float*)d_in[3];
    const float* b1    = (const float*)d_in[4];
    const float* w2    = (const float*)d_in[5];
    const float* b2    = (const float*)d_in[6];
    const float* w3    = (const float*)d_in[7];
    const float* b3    = (const float*)d_in[8];
    const float* query = (const float*)d_in[9];
    const float* lnqg  = (const float*)d_in[10];
    const float* lnqb  = (const float*)d_in[11];
    const float* lncg  = (const float*)d_in[12];
    const float* lncb  = (const float*)d_in[13];
    const float* wq    = (const float*)d_in[14];
    const float* wkv   = (const float*)d_in[15];
    const float* wo    = (const float*)d_in[16];
    const float* bo    = (const float*)d_in[17];
    const float* lnfg  = (const float*)d_in[18];
    const float* lnfb  = (const float*)d_in[19];
    const float* ffw1  = (const float*)d_in[20];
    const float* ffb1  = (const float*)d_in[21];
    const float* ffw2  = (const float*)d_in[22];
    const float* ffb2  = (const float*)d_in[23];
    float* out = (float*)d_out;
    char* wsb = (char*)d_ws;

    // ---- group size selection from ws_size (part fixed at 64 slots) ----
    auto need = [](int G) -> size_t {
        return (size_t)G * (3LL * 6291456 + 8388608)   // bufA,bufB,knT,P
             + 25165824                                // part (64 bf16 slots)
             + 6291456                                 // ao_all
             + 3 * 393216 + 32768                      // qn, qb, q2, den
             + 5898240;                                // weight pool
    };
    int G = 2;
    if      (ws_size >= need(16)) G = 16;
    else if (ws_size >= need(8))  G = 8;
    else if (ws_size >= need(4))  G = 4;
    const int SPLIT = 64 / G;

    long long off = 0;
    u16*   bufA   = (u16*)(wsb + off); off += (long long)G * 6291456;
    u16*   bufB   = (u16*)(wsb + off); off += (long long)G * 6291456;
    u16*   knT    = (u16*)(wsb + off); off += (long long)G * 6291456;
    u16*   Pb     = (u16*)(wsb + off); off += (long long)G * 8388608;
    u16*   part   = (u16*)(wsb + off); off += 25165824;
    u16*   ao_all = (u16*)(wsb + off); off += 6291456;
    u16*   qn     = (u16*)(wsb + off); off += 393216;
    u16*   qb     = (u16*)(wsb + off); off += 393216;
    u16*   q2     = (u16*)(wsb + off); off += 393216;
    float* den    = (float*)(wsb + off); off += 32768;
    u16*   w1T    = (u16*)(wsb + off); off += 294912;
    u16*   w2T    = (u16*)(wsb + off); off += 294912;
    u16*   w3T    = (u16*)(wsb + off); off += 294912;
    u16*   wqT    = (u16*)(wsb + off); off += 294912;
    u16*   woT    = (u16*)(wsb + off); off += 294912;
    u16*   ffw1T  = (u16*)(wsb + off); off += 2359296;
    u16*   ffw2T  = (u16*)(wsb + off); off += 1179648;
    u16*   wkdir  = (u16*)(wsb + off); off += 294912;   // wk natural layout
    u16*   wvdir  = (u16*)(wsb + off); off += 294912;   // wv natural layout
    u16*   wvoT   = (u16*)(wsb + off); off += 294912;   // (wv wo)^T
    // phase-2 overlays (bufA/bufB/knT region is dead by then)
    u16*   x1_all = (u16*)(wsb + 0);
    u16*   f0_all = (u16*)(wsb + 6291456);
    u16*   gl_all = (u16*)(wsb + 12582912);

    const int FULLMASK = 0x3FFFFFFF;

    // ---- setup ----
    wconv_all<<<10944, 256, 0, stream>>>(w1, w2, w3, wq, wkv, wo, ffw1, ffw2,
        w1T, w2T, w3T, wqT, woT, ffw1T, ffw2T, wkdir, wvdir);
    hipMemsetAsync(den, 0, 16 * 512 * sizeof(float), stream);
    ln_kernel<1><<<128, 256, 0, stream>>>(query, lnqg, lnqb, qn, 512);
    gemm_mfma<0, 0><<<dim3(4, 3), 256, 0, stream>>>(qn, wqT, nullptr, nullptr, qb,
        512, 384, 384, 384, 384, 384, 0, 1.f, 0, FULLMASK, 0, 0, 0);
    // q2 = scale * (qb @ wk^T): folds the K-projection into the query side.
    gemm_mfma<0, 0><<<dim3(4, 3), 256, 0, stream>>>(qb, wkdir, nullptr, nullptr, q2,
        512, 384, 384, 384, 384, 384, 0, 0.05103103630798288f, 0, FULLMASK, 0, 0, 0);
    // wvoT[o][d] = sum_c woT[o][c] * wv[d][c] = ((wv)(wo))^T
    gemm_mfma<0, 0><<<dim3(3, 3), 256, 0, stream>>>(woT, wvdir, nullptr, nullptr, wvoT,
        384, 384, 384, 384, 384, 384, 0, 1.f, 0, FULLMASK, 0, 0, 0);

    // ---- phase 1: groups of G batches ----
    const int MG = G * 8192;
    for (int base = 0; base < 16; base += G) {
        const float* xg = x + (long long)base * 24576;

        layer0_kernel<<<G * 3072, 256, 0, stream>>>(xg, w0, b0, bufA, G * 786432);
        gemm_mfma<0, 0><<<dim3(MG / 128, 3), 256, 0, stream>>>(bufA, w1T, b1, nullptr, bufB,
            MG, 384, 384, 384, 384, 384, 0, 1.f, 1, FULLMASK, 0, 0, 0);
        gemm_mfma<0, 0><<<dim3(MG / 128, 3), 256, 0, stream>>>(bufB, w2T, b2, nullptr, bufA,
            MG, 384, 384, 384, 384, 384, 0, 1.f, 1, FULLMASK, 0, 0, 0);
        gemm_mfma<0, 0><<<dim3(MG / 128, 3), 256, 0, stream>>>(bufA, w3T, b3, nullptr, bufB,
            MG, 384, 384, 384, 384, 384, 0, 1.f, 0, FULLMASK, 0, 0, 0);   // ctx -> bufB
        // kn (natural -> bufA) AND kn^T (-> knT) in one LayerNorm pass
        ln_tr_kernel<<<MG / 64, 256, 0, stream>>>(bufB, lncg, lncb, bufA, knT);
        // P_g = exp(q2 @ kn_g^T)  (kn consumed directly; scale in q2)
        gemm_exp<<<dim3(4, 64, G), 256, 0, stream>>>(q2, bufA, Pb, den + base * 512,
            384, 384, 384, 8192, 8192LL * 384, 512LL * 8192);
        // PV split-K partials: part = (P @ kn)/den via knT  (z = g*SPLIT + sp)
        gemm_pv<<<dim3(4, 3, G * SPLIT), 256, 0, stream>>>(Pb, knT, den + base * 512,
            part, SPLIT);
        // reduce -> ao_all[base..base+G)
        pv_reduce_kernel<<<G * 192, 256, 0, stream>>>(part,
            ao_all + (long long)base * 196608, SPLIT);
    }

    // ---- phase 2: batched across all 16 ----
    // x1 = ao2 @ (wv wo) + bo + lq   (V-projection folded into wvo)
    gemm_mfma<1, 0><<<dim3(64, 3), 256, 0, stream>>>(ao_all, wvoT, bo, query, x1_all,
        8192, 384, 384, 384, 384, 384, 384, 1.f, 0, 511, 0, 0, 0);
    ln_kernel<0><<<2048, 256, 0, stream>>>(x1_all, lnfg, lnfb, f0_all, 8192);
    gemm_ff1_geglu<<<dim3(64, 24), 256, 0, stream>>>(f0_all, ffw1T, ffb1, gl_all,
        384, 384, 384, 1536);
    gemm_mfma<0, 1><<<dim3(64, 3), 256, 0, stream>>>(gl_all, ffw2T, ffb2, x1_all, out,
        8192, 384, 1536, 1536, 1536, 384, 384, 1.f, 0, FULLMASK, 0, 0, 0);
}